// Round 2
// baseline (889.263 us; speedup 1.0000x reference)
//
#include <hip/hip_runtime.h>
#include <stdint.h>

typedef __bf16 bf16_t;
typedef __bf16 bf16x8 __attribute__((ext_vector_type(8)));
typedef float f32x4 __attribute__((ext_vector_type(4)));
typedef uint32_t u32x4 __attribute__((ext_vector_type(4)));

#define D_MODEL 1024
#define NH      16
#define DH      64
#define SEQ     2048
#define BATCH   4
#define MROWS   (BATCH * SEQ)   // 8192

// ---------------------------------------------------------------------------
// Transpose+convert 1024x1024 fp32 weights -> bf16: out[n][k] = (bf16)in[k][n]
// grid (32,32,4), block (32,8)
// ---------------------------------------------------------------------------
__global__ void transpose_w(const float* __restrict__ W0, const float* __restrict__ W1,
                            const float* __restrict__ W2, const float* __restrict__ W3,
                            bf16_t* __restrict__ out) {
    __shared__ bf16_t tile[32][33];
    const int z = blockIdx.z;
    const float* src = (z == 0) ? W0 : (z == 1) ? W1 : (z == 2) ? W2 : W3;
    bf16_t* dst = out + (size_t)z * (D_MODEL * D_MODEL);
    const int bx = blockIdx.x * 32, by = blockIdx.y * 32;
    const int tx = threadIdx.x, ty = threadIdx.y;
#pragma unroll
    for (int i = 0; i < 4; ++i)
        tile[ty + i * 8][tx] = (bf16_t)src[(size_t)(by + ty + i * 8) * D_MODEL + bx + tx];
    __syncthreads();
#pragma unroll
    for (int i = 0; i < 4; ++i)
        dst[(size_t)(bx + ty + i * 8) * D_MODEL + by + tx] = tile[tx][ty + i * 8];
}

// ---------------------------------------------------------------------------
// Projection GEMM: C[m][n] = (sum_k A[m][k]*Wt[n][k] + bias[n]) * scale
// A: (M x 1024) row-major (fp32 or bf16 per template), Wt: bf16 (= W^T)
// OUT_MODE: 0 = bf16 row-major [m][1024]
//           1 = f32  row-major [m][1024]
//           2 = bf16 per-head transposed: out[((b*16+h)*64+d)*2048 + s]
//               (m = b*2048+s, n = h*64+d)  -- feeds flash_attn's V^T operand
// grid (N/128=8, M/128), block 256 (4 waves, 2x2 of 64x64)
// ---------------------------------------------------------------------------
#define LDS_STRIDE 40
template<bool A_IS_F32, int OUT_MODE>
__global__ __launch_bounds__(256) void proj_gemm(const void* __restrict__ A_,
                                                 const bf16_t* __restrict__ Wt,
                                                 const float* __restrict__ bias,
                                                 void* __restrict__ C_,
                                                 float scale) {
    __shared__ __align__(16) bf16_t As[128 * LDS_STRIDE];
    __shared__ __align__(16) bf16_t Bs[128 * LDS_STRIDE];
    const int tid  = threadIdx.x;
    const int lane = tid & 63;
    const int w    = tid >> 6;           // wave 0..3
    const int wrow = (w >> 1) * 64;
    const int wcol = (w & 1) * 64;
    const int m0 = blockIdx.y * 128;
    const int n0 = blockIdx.x * 128;
    const int l15  = lane & 15;
    const int quad = lane >> 4;
    const int srow = tid >> 2;           // 0..63
    const int sq   = (tid & 3) * 8;      // 0,8,16,24

    f32x4 acc[4][4];
#pragma unroll
    for (int i = 0; i < 4; ++i)
#pragma unroll
        for (int j = 0; j < 4; ++j)
#pragma unroll
            for (int r = 0; r < 4; ++r) acc[i][j][r] = 0.0f;

    for (int kt = 0; kt < 32; ++kt) {
        const int k0 = kt * 32;
#pragma unroll
        for (int rd = 0; rd < 2; ++rd) {
            const int row = rd * 64 + srow;
            if (A_IS_F32) {
                const float* A = (const float*)A_;
                const float4 x = *(const float4*)(A + (size_t)(m0 + row) * D_MODEL + k0 + sq);
                const float4 y = *(const float4*)(A + (size_t)(m0 + row) * D_MODEL + k0 + sq + 4);
                bf16x8 t;
                t[0] = (bf16_t)x.x; t[1] = (bf16_t)x.y; t[2] = (bf16_t)x.z; t[3] = (bf16_t)x.w;
                t[4] = (bf16_t)y.x; t[5] = (bf16_t)y.y; t[6] = (bf16_t)y.z; t[7] = (bf16_t)y.w;
                *(bf16x8*)&As[row * LDS_STRIDE + sq] = t;
            } else {
                const bf16_t* A = (const bf16_t*)A_;
                *(bf16x8*)&As[row * LDS_STRIDE + sq] =
                    *(const bf16x8*)(A + (size_t)(m0 + row) * D_MODEL + k0 + sq);
            }
            *(bf16x8*)&Bs[row * LDS_STRIDE + sq] =
                *(const bf16x8*)(Wt + (size_t)(n0 + row) * D_MODEL + k0 + sq);
        }
        __syncthreads();
        bf16x8 af[4], bf[4];
#pragma unroll
        for (int mi = 0; mi < 4; ++mi)
            af[mi] = *(const bf16x8*)&As[(wrow + mi * 16 + l15) * LDS_STRIDE + quad * 8];
#pragma unroll
        for (int ni = 0; ni < 4; ++ni)
            bf[ni] = *(const bf16x8*)&Bs[(wcol + ni * 16 + l15) * LDS_STRIDE + quad * 8];
#pragma unroll
        for (int mi = 0; mi < 4; ++mi)
#pragma unroll
            for (int ni = 0; ni < 4; ++ni)
                acc[mi][ni] = __builtin_amdgcn_mfma_f32_16x16x32_bf16(af[mi], bf[ni], acc[mi][ni], 0, 0, 0);
        __syncthreads();
    }

#pragma unroll
    for (int ni = 0; ni < 4; ++ni) {
        const int col = n0 + wcol + ni * 16 + l15;
        const float bc = bias[col];
#pragma unroll
        for (int mi = 0; mi < 4; ++mi) {
#pragma unroll
            for (int r = 0; r < 4; ++r) {
                const int row = m0 + wrow + mi * 16 + quad * 4 + r;
                const float v = (acc[mi][ni][r] + bc) * scale;
                if (OUT_MODE == 1) {
                    ((float*)C_)[(size_t)row * D_MODEL + col] = v;
                } else if (OUT_MODE == 0) {
                    ((bf16_t*)C_)[(size_t)row * D_MODEL + col] = (bf16_t)v;
                } else {
                    // per-head transposed: [(b*16+h)*64+d][2048] <- (row=b*2048+s, col=h*64+d)
                    const int bb = row >> 11, ss = row & 2047;
                    const int hh = col >> 6,  dd = col & 63;
                    ((bf16_t*)C_)[((size_t)(bb * 16 + hh) * 64 + dd) * 2048 + ss] = (bf16_t)v;
                }
            }
        }
    }
}

// ---------------------------------------------------------------------------
// pack two floats into one dword of 2 bf16 (lo = a, hi = b)
// ---------------------------------------------------------------------------
__device__ __forceinline__ uint32_t pk2(float a, float b) {
    union { bf16_t h[2]; uint32_t u; } x;
    x.h[0] = (bf16_t)a; x.h[1] = (bf16_t)b;
    return x.u;
}

// ---------------------------------------------------------------------------
// Flash attention, LDS-free: grid (32 q-tiles, 64 bh), block 256 (4 indep waves)
//   Q,K: bf16 row-major [b][seq][1024] (head offset h*64)
//   Vt:  bf16 per-head transposed [bh][d=64][seq=2048]  (from proj OUT_MODE=2)
//   ctx: bf16 row-major [b*2048+q][1024]
// QK^T computed swapped: s = mfma(K, Q) -> S^T[k][q], q = lane&15 (lane-local
// softmax row). P^T transposed back to the PV A-layout in-register via
// pack + 16 shfl + target-side select per k-tile. No LDS, no barriers.
// NOTE: __shfl evaluates its operand in the SOURCE lane, so the ki selection
// (ki = 2*ks + (quad_target>>1)) must happen on the TARGET side after
// shuffling BOTH candidates (round-1 bug: source-side ternary delivered
// ki = 2*ks + (quad_target&1) -> quads 1,2 got swapped k-halves).
// ---------------------------------------------------------------------------
__global__ __launch_bounds__(256) void flash_attn(const bf16_t* __restrict__ Qu,
                                                  const bf16_t* __restrict__ Ku,
                                                  const bf16_t* __restrict__ Vt,
                                                  bf16_t* __restrict__ ctx) {
    const int qt = blockIdx.x;           // 0..31
    const int bh = blockIdx.y;           // 0..63
    const int b = bh >> 4, h = bh & 15;
    const int tid  = threadIdx.x;
    const int lane = tid & 63;
    const int w    = tid >> 6;
    const int l15  = lane & 15;
    const int quad = lane >> 4;

    const size_t base_qk = (size_t)b * SEQ * D_MODEL + (size_t)h * DH;
    const size_t base_v  = (size_t)bh * DH * SEQ;
    const int qrow0 = qt * 64 + w * 16;

    // Q fragment (B-operand of swapped QK): rows q on l15, feature on quad*8
    bf16x8 qf[2];
#pragma unroll
    for (int ks = 0; ks < 2; ++ks)
        qf[ks] = *(const bf16x8*)(Qu + base_qk + (size_t)(qrow0 + l15) * D_MODEL + ks * 32 + quad * 8);

    // per-lane base pointers (32 k-tile advances are additive offsets)
    const bf16_t* kbase = Ku + base_qk + (size_t)l15 * D_MODEL + quad * 8;
    const bf16_t* vbase = Vt + base_v + (size_t)l15 * SEQ + quad * 8;

    float m_q = -__builtin_inff();       // running max for q = l15 (replicated over quads)
    float l_q = 0.0f;                    // running sum for q = l15
    f32x4 cacc[4];
#pragma unroll
    for (int ds = 0; ds < 4; ++ds)
#pragma unroll
        for (int r = 0; r < 4; ++r) cacc[ds][r] = 0.0f;

    for (int kt = 0; kt < 32; ++kt) {
        const int kb = kt * 64;

        // ---- QK^T swapped: s[ki][r] = S^T[k = kb + ki*16 + quad*4 + r][q = qrow0 + l15]
        f32x4 s[4];
#pragma unroll
        for (int ki = 0; ki < 4; ++ki)
#pragma unroll
            for (int r = 0; r < 4; ++r) s[ki][r] = 0.0f;
#pragma unroll
        for (int ks = 0; ks < 2; ++ks)
#pragma unroll
            for (int ki = 0; ki < 4; ++ki) {
                bf16x8 kf = *(const bf16x8*)(kbase + (size_t)(kb + ki * 16) * D_MODEL + ks * 32);
                s[ki] = __builtin_amdgcn_mfma_f32_16x16x32_bf16(kf, qf[ks], s[ki], 0, 0, 0);
            }

        // ---- V^T fragments (B-operand of PV): d on l15 (+ds*16), k on quad*8
        // issued here so the ~L2 latency hides under softmax + exchange
        bf16x8 vf[4][2];
#pragma unroll
        for (int ds = 0; ds < 4; ++ds)
#pragma unroll
            for (int ks = 0; ks < 2; ++ks)
                vf[ds][ks] = *(const bf16x8*)(vbase + (size_t)(ds * 16) * SEQ + kb + ks * 32);

        // ---- online softmax for q = l15: 16 lane-local values + 2 shfl_xor
        float v = s[0][0];
#pragma unroll
        for (int ki = 0; ki < 4; ++ki)
#pragma unroll
            for (int r = 0; r < 4; ++r) v = fmaxf(v, s[ki][r]);
        v = fmaxf(v, __shfl_xor(v, 16));
        v = fmaxf(v, __shfl_xor(v, 32));
        const float mn  = fmaxf(m_q, v);
        const float alq = __expf(m_q - mn);
        m_q = mn;

        float t = 0.0f;
        uint32_t pk_[4][2];              // pk_[ki][0]=(r0,r1) pk_[ki][1]=(r2,r3), bf16 pairs
#pragma unroll
        for (int ki = 0; ki < 4; ++ki) {
            const float p0 = __expf(s[ki][0] - mn);
            const float p1 = __expf(s[ki][1] - mn);
            const float p2 = __expf(s[ki][2] - mn);
            const float p3 = __expf(s[ki][3] - mn);
            t += (p0 + p1) + (p2 + p3);
            pk_[ki][0] = pk2(p0, p1);
            pk_[ki][1] = pk2(p2, p3);
        }
        t += __shfl_xor(t, 16);
        t += __shfl_xor(t, 32);
        l_q = l_q * alq + t;

        // ---- rescale cacc: its rows are q = quad*4 + r -> fetch al from lane q
        float al_c[4];
#pragma unroll
        for (int r = 0; r < 4; ++r) al_c[r] = __shfl(alq, quad * 4 + r, 16);
#pragma unroll
        for (int ds = 0; ds < 4; ++ds)
#pragma unroll
            for (int r = 0; r < 4; ++r) cacc[ds][r] *= al_c[r];

        // ---- in-register P^T -> A-layout: af[ks][j] = P[q=l15][k=ks*32+quad*8+j]
        // source lane: l15 + 32*(quad&1) + 16*(j>>2); source reg ki = 2*ks + (quad>>1),
        // pair = (j>>2 selects lane, j&3 -> r within pk pair dwords).
        // Shuffle BOTH ki candidates, select by target quad bit1.
        const int srcA = l15 + ((quad & 1) << 5);
        const bool hi  = (quad & 2) != 0;
        bf16x8 af[2];
#pragma unroll
        for (int ks = 0; ks < 2; ++ks) {
            const uint32_t a0 = pk_[2 * ks][0],     a1 = pk_[2 * ks][1];
            const uint32_t b0 = pk_[2 * ks + 1][0], b1 = pk_[2 * ks + 1][1];
            union { u32x4 d; bf16x8 v8; } cv;
            const uint32_t xa = (uint32_t)__shfl((int)a0, srcA);
            const uint32_t xb = (uint32_t)__shfl((int)b0, srcA);
            cv.d.x = hi ? xb : xa;                               // j0,j1 (r0,r1)
            const uint32_t ya = (uint32_t)__shfl((int)a1, srcA);
            const uint32_t yb = (uint32_t)__shfl((int)b1, srcA);
            cv.d.y = hi ? yb : ya;                               // j2,j3 (r2,r3)
            const uint32_t za = (uint32_t)__shfl((int)a0, srcA + 16);
            const uint32_t zb = (uint32_t)__shfl((int)b0, srcA + 16);
            cv.d.z = hi ? zb : za;                               // j4,j5
            const uint32_t wa = (uint32_t)__shfl((int)a1, srcA + 16);
            const uint32_t wb = (uint32_t)__shfl((int)b1, srcA + 16);
            cv.d.w = hi ? wb : wa;                               // j6,j7
            af[ks] = cv.v8;
        }

        // ---- PV: cacc[ds] += P[q][k] * V^T[d][k]
#pragma unroll
        for (int ds = 0; ds < 4; ++ds)
#pragma unroll
            for (int ks = 0; ks < 2; ++ks)
                cacc[ds] = __builtin_amdgcn_mfma_f32_16x16x32_bf16(af[ks], vf[ds][ks], cacc[ds], 0, 0, 0);
    }

    // ---- epilogue: rows of cacc are q = quad*4 + r -> fetch l from lane q
    float l_c[4];
#pragma unroll
    for (int r = 0; r < 4; ++r) l_c[r] = __shfl(l_q, quad * 4 + r, 16);
#pragma unroll
    for (int r = 0; r < 4; ++r) {
        const float rl = 1.0f / l_c[r];
        const int q = qrow0 + quad * 4 + r;
#pragma unroll
        for (int ds = 0; ds < 4; ++ds)
            ctx[(size_t)(b * SEQ + q) * D_MODEL + h * DH + ds * 16 + l15] = (bf16_t)(cacc[ds][r] * rl);
    }
}

// ---------------------------------------------------------------------------
// Head-0 attention matrix, recomputed: grid (32 q-tiles, 4 b), block 256.
// Pass A: running max/sum over keys. Pass B: write exp(s-m)/l as FP32.
// ---------------------------------------------------------------------------
__global__ __launch_bounds__(256) void attn_h0(const bf16_t* __restrict__ Qu,
                                               const bf16_t* __restrict__ Ku,
                                               float* __restrict__ out) {
    const int qt = blockIdx.x;           // 0..31
    const int b  = blockIdx.y;           // 0..3
    const int tid  = threadIdx.x;
    const int lane = tid & 63;
    const int w    = tid >> 6;
    const int l15  = lane & 15;
    const int quad = lane >> 4;

    const size_t base_b = (size_t)b * SEQ * D_MODEL;   // head 0
    const int qrow0 = qt * 64 + w * 16;

    bf16x8 qf[2];
#pragma unroll
    for (int ks = 0; ks < 2; ++ks)
        qf[ks] = *(const bf16x8*)(Qu + base_b + (size_t)(qrow0 + l15) * D_MODEL + ks * 32 + quad * 8);

    float m_r[4], l_r[4];
#pragma unroll
    for (int r = 0; r < 4; ++r) { m_r[r] = -__builtin_inff(); l_r[r] = 0.0f; }

    // Pass A: running max & sum
    for (int kt = 0; kt < 32; ++kt) {
        const int kb = kt * 64;
        f32x4 s[4];
#pragma unroll
        for (int ki = 0; ki < 4; ++ki)
#pragma unroll
            for (int r = 0; r < 4; ++r) s[ki][r] = 0.0f;
#pragma unroll
        for (int ks = 0; ks < 2; ++ks)
#pragma unroll
            for (int ki = 0; ki < 4; ++ki) {
                bf16x8 kf = *(const bf16x8*)(Ku + base_b + (size_t)(kb + ki * 16 + l15) * D_MODEL + ks * 32 + quad * 8);
                s[ki] = __builtin_amdgcn_mfma_f32_16x16x32_bf16(qf[ks], kf, s[ki], 0, 0, 0);
            }
#pragma unroll
        for (int r = 0; r < 4; ++r) {
            float v = fmaxf(fmaxf(s[0][r], s[1][r]), fmaxf(s[2][r], s[3][r]));
#pragma unroll
            for (int off = 1; off < 16; off <<= 1) v = fmaxf(v, __shfl_xor(v, off, 16));
            const float mn = fmaxf(m_r[r], v);
            const float al = __expf(m_r[r] - mn);
            m_r[r] = mn;
            float t = __expf(s[0][r] - mn) + __expf(s[1][r] - mn)
                    + __expf(s[2][r] - mn) + __expf(s[3][r] - mn);
#pragma unroll
            for (int off = 1; off < 16; off <<= 1) t += __shfl_xor(t, off, 16);
            l_r[r] = l_r[r] * al + t;
        }
    }
    float rl[4];
#pragma unroll
    for (int r = 0; r < 4; ++r) rl[r] = 1.0f / l_r[r];

    // Pass B: recompute and write normalized probabilities (fp32)
    for (int kt = 0; kt < 32; ++kt) {
        const int kb = kt * 64;
        f32x4 s[4];
#pragma unroll
        for (int ki = 0; ki < 4; ++ki)
#pragma unroll
            for (int r = 0; r < 4; ++r) s[ki][r] = 0.0f;
#pragma unroll
        for (int ks = 0; ks < 2; ++ks)
#pragma unroll
            for (int ki = 0; ki < 4; ++ki) {
                bf16x8 kf = *(const bf16x8*)(Ku + base_b + (size_t)(kb + ki * 16 + l15) * D_MODEL + ks * 32 + quad * 8);
                s[ki] = __builtin_amdgcn_mfma_f32_16x16x32_bf16(qf[ks], kf, s[ki], 0, 0, 0);
            }
#pragma unroll
        for (int ki = 0; ki < 4; ++ki)
#pragma unroll
            for (int r = 0; r < 4; ++r) {
                const int q = qrow0 + quad * 4 + r;
                out[(size_t)(b * SEQ + q) * SEQ + kb + ki * 16 + l15] =
                    __expf(s[ki][r] - m_r[r]) * rl[r];
            }
    }
}

// ---------------------------------------------------------------------------
extern "C" void kernel_launch(void* const* d_in, const int* in_sizes, int n_in,
                              void* d_out, int out_size, void* d_ws, size_t ws_size,
                              hipStream_t stream) {
    // All inputs/outputs are FP32 (per reference). Internally bf16 MFMA.
    const float* key   = (const float*)d_in[0];
    const float* value = (const float*)d_in[1];
    const float* query = (const float*)d_in[2];
    const float* Wk = (const float*)d_in[3];
    const float* bk = (const float*)d_in[4];
    const float* Wv = (const float*)d_in[5];
    const float* bv = (const float*)d_in[6];
    const float* Wq = (const float*)d_in[7];
    const float* bq = (const float*)d_in[8];
    const float* Wo = (const float*)d_in[9];
    const float* bo = (const float*)d_in[10];

    float* out_proj = (float*)d_out;                            // 8388608 fp32 (32 MiB)
    float* out_attn = (float*)d_out + (size_t)MROWS * D_MODEL;  // 16777216 fp32 (64 MiB)

    // ws layout (40 MiB): Wt(8) | Kup(16) | Qup(16)   [all bf16]
    char* ws = (char*)d_ws;
    bf16_t* Wt  = (bf16_t*)ws;
    bf16_t* Kup = (bf16_t*)(ws + (size_t) 8 * 1024 * 1024);
    bf16_t* Qup = (bf16_t*)(ws + (size_t)24 * 1024 * 1024);
    // Vt_g (V^T per head, 16 MiB) and ctx (16 MiB) live inside the 64 MiB
    // out_attn region; both are dead before attn_h0 overwrites it at the end.
    bf16_t* Vt_g = (bf16_t*)out_attn;
    bf16_t* ctx  = Vt_g + (size_t)MROWS * D_MODEL;

    const bf16_t* Wt_k = Wt;
    const bf16_t* Wt_v = Wt + 1 * D_MODEL * D_MODEL;
    const bf16_t* Wt_q = Wt + 2 * D_MODEL * D_MODEL;
    const bf16_t* Wt_o = Wt + 3 * D_MODEL * D_MODEL;

    transpose_w<<<dim3(32, 32, 4), dim3(32, 8), 0, stream>>>(Wk, Wv, Wq, Wo, Wt);

    proj_gemm<true,  0><<<dim3(8, 64), 256, 0, stream>>>(key,   Wt_k, bk, Kup,  1.0f);
    proj_gemm<true,  2><<<dim3(8, 64), 256, 0, stream>>>(value, Wt_v, bv, Vt_g, 1.0f);   // writes V^T per head
    proj_gemm<true,  0><<<dim3(8, 64), 256, 0, stream>>>(query, Wt_q, bq, Qup,  0.125f); // 1/sqrt(64)

    flash_attn<<<dim3(32, 64), 256, 0, stream>>>(Qup, Kup, Vt_g, ctx);

    proj_gemm<false, 1><<<dim3(8, 64), 256, 0, stream>>>(ctx, Wt_o, bo, out_proj, 1.0f);

    attn_h0<<<dim3(32, 4), 256, 0, stream>>>(Qup, Kup, out_attn);
}

// Round 3
// 882.828 us; speedup vs baseline: 1.0073x; 1.0073x over previous
//
#include <hip/hip_runtime.h>
#include <stdint.h>

typedef __bf16 bf16_t;
typedef __bf16 bf16x8 __attribute__((ext_vector_type(8)));
typedef float f32x4 __attribute__((ext_vector_type(4)));

#define D_MODEL 1024
#define NH      16
#define DH      64
#define SEQ     2048
#define BATCH   4
#define MROWS   (BATCH * SEQ)   // 8192

// ---------------------------------------------------------------------------
// Transpose+convert 1024x1024 fp32 weights -> bf16: out[n][k] = (bf16)in[k][n]
// grid (32,32,4), block (32,8)
// ---------------------------------------------------------------------------
__global__ void transpose_w(const float* __restrict__ W0, const float* __restrict__ W1,
                            const float* __restrict__ W2, const float* __restrict__ W3,
                            bf16_t* __restrict__ out) {
    __shared__ bf16_t tile[32][33];
    const int z = blockIdx.z;
    const float* src = (z == 0) ? W0 : (z == 1) ? W1 : (z == 2) ? W2 : W3;
    bf16_t* dst = out + (size_t)z * (D_MODEL * D_MODEL);
    const int bx = blockIdx.x * 32, by = blockIdx.y * 32;
    const int tx = threadIdx.x, ty = threadIdx.y;
#pragma unroll
    for (int i = 0; i < 4; ++i)
        tile[ty + i * 8][tx] = (bf16_t)src[(size_t)(by + ty + i * 8) * D_MODEL + bx + tx];
    __syncthreads();
#pragma unroll
    for (int i = 0; i < 4; ++i)
        dst[(size_t)(bx + ty + i * 8) * D_MODEL + by + tx] = tile[tx][ty + i * 8];
}

// ---------------------------------------------------------------------------
// Projection GEMM: C[m][n] = (sum_k A[m][k]*Wt[n][k] + bias[n]) * scale
// A: (M x 1024) row-major (fp32 or bf16 per template), Wt: bf16 (= W^T)
// OUT_MODE: 0 = bf16 row-major [m][1024]
//           1 = f32  row-major [m][1024]
//           2 = bf16 per-head transposed: out[((b*16+h)*64+d)*2048 + s]
//               (m = b*2048+s, n = h*64+d)  -- feeds flash_attn's V^T operand
// grid (N/128=8, M/128), block 256 (4 waves, 2x2 of 64x64)
// ---------------------------------------------------------------------------
#define LDS_STRIDE 40
template<bool A_IS_F32, int OUT_MODE>
__global__ __launch_bounds__(256) void proj_gemm(const void* __restrict__ A_,
                                                 const bf16_t* __restrict__ Wt,
                                                 const float* __restrict__ bias,
                                                 void* __restrict__ C_,
                                                 float scale) {
    __shared__ __align__(16) bf16_t As[128 * LDS_STRIDE];
    __shared__ __align__(16) bf16_t Bs[128 * LDS_STRIDE];
    const int tid  = threadIdx.x;
    const int lane = tid & 63;
    const int w    = tid >> 6;           // wave 0..3
    const int wrow = (w >> 1) * 64;
    const int wcol = (w & 1) * 64;
    const int m0 = blockIdx.y * 128;
    const int n0 = blockIdx.x * 128;
    const int l15  = lane & 15;
    const int quad = lane >> 4;
    const int srow = tid >> 2;           // 0..63
    const int sq   = (tid & 3) * 8;      // 0,8,16,24

    f32x4 acc[4][4];
#pragma unroll
    for (int i = 0; i < 4; ++i)
#pragma unroll
        for (int j = 0; j < 4; ++j)
#pragma unroll
            for (int r = 0; r < 4; ++r) acc[i][j][r] = 0.0f;

    for (int kt = 0; kt < 32; ++kt) {
        const int k0 = kt * 32;
#pragma unroll
        for (int rd = 0; rd < 2; ++rd) {
            const int row = rd * 64 + srow;
            if (A_IS_F32) {
                const float* A = (const float*)A_;
                const float4 x = *(const float4*)(A + (size_t)(m0 + row) * D_MODEL + k0 + sq);
                const float4 y = *(const float4*)(A + (size_t)(m0 + row) * D_MODEL + k0 + sq + 4);
                bf16x8 t;
                t[0] = (bf16_t)x.x; t[1] = (bf16_t)x.y; t[2] = (bf16_t)x.z; t[3] = (bf16_t)x.w;
                t[4] = (bf16_t)y.x; t[5] = (bf16_t)y.y; t[6] = (bf16_t)y.z; t[7] = (bf16_t)y.w;
                *(bf16x8*)&As[row * LDS_STRIDE + sq] = t;
            } else {
                const bf16_t* A = (const bf16_t*)A_;
                *(bf16x8*)&As[row * LDS_STRIDE + sq] =
                    *(const bf16x8*)(A + (size_t)(m0 + row) * D_MODEL + k0 + sq);
            }
            *(bf16x8*)&Bs[row * LDS_STRIDE + sq] =
                *(const bf16x8*)(Wt + (size_t)(n0 + row) * D_MODEL + k0 + sq);
        }
        __syncthreads();
        bf16x8 af[4], bf[4];
#pragma unroll
        for (int mi = 0; mi < 4; ++mi)
            af[mi] = *(const bf16x8*)&As[(wrow + mi * 16 + l15) * LDS_STRIDE + quad * 8];
#pragma unroll
        for (int ni = 0; ni < 4; ++ni)
            bf[ni] = *(const bf16x8*)&Bs[(wcol + ni * 16 + l15) * LDS_STRIDE + quad * 8];
#pragma unroll
        for (int mi = 0; mi < 4; ++mi)
#pragma unroll
            for (int ni = 0; ni < 4; ++ni)
                acc[mi][ni] = __builtin_amdgcn_mfma_f32_16x16x32_bf16(af[mi], bf[ni], acc[mi][ni], 0, 0, 0);
        __syncthreads();
    }

#pragma unroll
    for (int ni = 0; ni < 4; ++ni) {
        const int col = n0 + wcol + ni * 16 + l15;
        const float bc = bias[col];
#pragma unroll
        for (int mi = 0; mi < 4; ++mi) {
#pragma unroll
            for (int r = 0; r < 4; ++r) {
                const int row = m0 + wrow + mi * 16 + quad * 4 + r;
                const float v = (acc[mi][ni][r] + bc) * scale;
                if (OUT_MODE == 1) {
                    ((float*)C_)[(size_t)row * D_MODEL + col] = v;
                } else if (OUT_MODE == 0) {
                    ((bf16_t*)C_)[(size_t)row * D_MODEL + col] = (bf16_t)v;
                } else {
                    // per-head transposed: [(b*16+h)*64+d][2048] <- (row=b*2048+s, col=h*64+d)
                    const int bb = row >> 11, ss = row & 2047;
                    const int hh = col >> 6,  dd = col & 63;
                    ((bf16_t*)C_)[((size_t)(bb * 16 + hh) * 64 + dd) * 2048 + ss] = (bf16_t)v;
                }
            }
        }
    }
}

// ---------------------------------------------------------------------------
// Flash attention v3 (hybrid of r0 + r2): grid (32 q-tiles, 64 bh), block 256
//   Q,K: bf16 row-major [b][seq][1024] (head offset h*64)
//   Vt:  bf16 per-head transposed [bh][d=64][seq=2048]  (proj OUT_MODE=2)
//   ctx: bf16 row-major [b*2048+q][1024]
// Normal-orientation QK (S rows q=quad*4+r, cols k=ki*16+l15) -> per-row
// online softmax (no cross-row shuffles for rescale) -> P via wave-private
// LDS round-trip (no barriers: Ps[w] is per-wave; waitcnt orders ds ops) ->
// PV with V^T fragments loaded directly from global (L2-resident, 256KB/bh).
// r2 post-mortem: the LDS-free exchange made one long serial chain and
// exposed global latency (VGPR pressure killed prefetch) -> 535us. The r0
// cost was the V-transpose staging's 4-way-conflict scalar stores, now gone.
// ---------------------------------------------------------------------------
__global__ __launch_bounds__(256) void flash_attn(const bf16_t* __restrict__ Qu,
                                                  const bf16_t* __restrict__ Ku,
                                                  const bf16_t* __restrict__ Vt,
                                                  bf16_t* __restrict__ ctx) {
    const int qt = blockIdx.x;           // 0..31
    const int bh = blockIdx.y;           // 0..63
    const int b = bh >> 4, h = bh & 15;
    const int tid  = threadIdx.x;
    const int lane = tid & 63;
    const int w    = tid >> 6;
    const int l15  = lane & 15;
    const int quad = lane >> 4;

    __shared__ __align__(16) bf16_t Ps[4][16][72];    // [wave][q][key], wave-private

    const size_t base_qk = (size_t)b * SEQ * D_MODEL + (size_t)h * DH;
    const size_t base_v  = (size_t)bh * DH * SEQ;
    const int qrow0 = qt * 64 + w * 16;

    // Q fragment (A-operand): rows q on l15, feature on quad*8
    bf16x8 qf[2];
#pragma unroll
    for (int ks = 0; ks < 2; ++ks)
        qf[ks] = *(const bf16x8*)(Qu + base_qk + (size_t)(qrow0 + l15) * D_MODEL + ks * 32 + quad * 8);

    const bf16_t* kbase = Ku + base_qk + (size_t)l15 * D_MODEL + quad * 8;
    const bf16_t* vbase = Vt + base_v + (size_t)l15 * SEQ + quad * 8;

    float m_r[4], l_r[4];
    f32x4 cacc[4];
#pragma unroll
    for (int r = 0; r < 4; ++r) { m_r[r] = -__builtin_inff(); l_r[r] = 0.0f; }
#pragma unroll
    for (int ds = 0; ds < 4; ++ds)
#pragma unroll
        for (int r = 0; r < 4; ++r) cacc[ds][r] = 0.0f;

    for (int kt = 0; kt < 32; ++kt) {
        const int kb = kt * 64;

        // ---- QK^T: s[ki][r] = S[q = quad*4 + r][k = ki*16 + l15]
        f32x4 s[4];
#pragma unroll
        for (int ki = 0; ki < 4; ++ki)
#pragma unroll
            for (int r = 0; r < 4; ++r) s[ki][r] = 0.0f;
#pragma unroll
        for (int ks = 0; ks < 2; ++ks)
#pragma unroll
            for (int ki = 0; ki < 4; ++ki) {
                bf16x8 kf = *(const bf16x8*)(kbase + (size_t)(kb + ki * 16) * D_MODEL + ks * 32);
                s[ki] = __builtin_amdgcn_mfma_f32_16x16x32_bf16(qf[ks], kf, s[ki], 0, 0, 0);
            }

        // ---- V^T fragments (B-operand of PV): d on l15 (+ds*16), k on quad*8
        // issued here so the L2 latency hides under softmax + Ps round-trip
        bf16x8 vf[4][2];
#pragma unroll
        for (int ds = 0; ds < 4; ++ds)
#pragma unroll
            for (int ks = 0; ks < 2; ++ks)
                vf[ds][ks] = *(const bf16x8*)(vbase + (size_t)(ds * 16) * SEQ + kb + ks * 32);

        // ---- online softmax per output row r (rows q = quad*4+r)
        float mn[4], al[4];
#pragma unroll
        for (int r = 0; r < 4; ++r) {
            float v = fmaxf(fmaxf(s[0][r], s[1][r]), fmaxf(s[2][r], s[3][r]));
#pragma unroll
            for (int off = 1; off < 16; off <<= 1) v = fmaxf(v, __shfl_xor(v, off, 16));
            mn[r] = fmaxf(m_r[r], v);
            al[r] = __expf(m_r[r] - mn[r]);
            m_r[r] = mn[r];
        }
        float p[4][4];
#pragma unroll
        for (int ki = 0; ki < 4; ++ki)
#pragma unroll
            for (int r = 0; r < 4; ++r) p[ki][r] = __expf(s[ki][r] - mn[r]);
#pragma unroll
        for (int r = 0; r < 4; ++r) {
            float t = p[0][r] + p[1][r] + p[2][r] + p[3][r];
#pragma unroll
            for (int off = 1; off < 16; off <<= 1) t += __shfl_xor(t, off, 16);
            l_r[r] = l_r[r] * al[r] + t;
        }
#pragma unroll
        for (int ds = 0; ds < 4; ++ds)
#pragma unroll
            for (int r = 0; r < 4; ++r) cacc[ds][r] *= al[r];

        // ---- P -> wave-private LDS (bf16); waitcnt (not a barrier) orders this
        #pragma unroll
        for (int ki = 0; ki < 4; ++ki)
#pragma unroll
            for (int r = 0; r < 4; ++r)
                Ps[w][quad * 4 + r][ki * 16 + l15] = (bf16_t)p[ki][r];

        // ---- PV: A = P[q=l15][k], B = V^T[d][k]
#pragma unroll
        for (int ks = 0; ks < 2; ++ks) {
            bf16x8 af = *(const bf16x8*)&Ps[w][l15][ks * 32 + quad * 8];
#pragma unroll
            for (int ds = 0; ds < 4; ++ds)
                cacc[ds] = __builtin_amdgcn_mfma_f32_16x16x32_bf16(af, vf[ds][ks], cacc[ds], 0, 0, 0);
        }
    }

    // ---- epilogue: rows of cacc are q = quad*4 + r (same rows as m_r/l_r)
#pragma unroll
    for (int r = 0; r < 4; ++r) {
        const float rl = 1.0f / l_r[r];
        const int q = qrow0 + quad * 4 + r;
#pragma unroll
        for (int ds = 0; ds < 4; ++ds)
            ctx[(size_t)(b * SEQ + q) * D_MODEL + h * DH + ds * 16 + l15] = (bf16_t)(cacc[ds][r] * rl);
    }
}

// ---------------------------------------------------------------------------
// Head-0 attention matrix, recomputed: grid (32 q-tiles, 4 b), block 256.
// Pass A: running max/sum over keys. Pass B: write exp(s-m)/l as FP32.
// ---------------------------------------------------------------------------
__global__ __launch_bounds__(256) void attn_h0(const bf16_t* __restrict__ Qu,
                                               const bf16_t* __restrict__ Ku,
                                               float* __restrict__ out) {
    const int qt = blockIdx.x;           // 0..31
    const int b  = blockIdx.y;           // 0..3
    const int tid  = threadIdx.x;
    const int lane = tid & 63;
    const int w    = tid >> 6;
    const int l15  = lane & 15;
    const int quad = lane >> 4;

    const size_t base_b = (size_t)b * SEQ * D_MODEL;   // head 0
    const int qrow0 = qt * 64 + w * 16;

    bf16x8 qf[2];
#pragma unroll
    for (int ks = 0; ks < 2; ++ks)
        qf[ks] = *(const bf16x8*)(Qu + base_b + (size_t)(qrow0 + l15) * D_MODEL + ks * 32 + quad * 8);

    float m_r[4], l_r[4];
#pragma unroll
    for (int r = 0; r < 4; ++r) { m_r[r] = -__builtin_inff(); l_r[r] = 0.0f; }

    // Pass A: running max & sum
    for (int kt = 0; kt < 32; ++kt) {
        const int kb = kt * 64;
        f32x4 s[4];
#pragma unroll
        for (int ki = 0; ki < 4; ++ki)
#pragma unroll
            for (int r = 0; r < 4; ++r) s[ki][r] = 0.0f;
#pragma unroll
        for (int ks = 0; ks < 2; ++ks)
#pragma unroll
            for (int ki = 0; ki < 4; ++ki) {
                bf16x8 kf = *(const bf16x8*)(Ku + base_b + (size_t)(kb + ki * 16 + l15) * D_MODEL + ks * 32 + quad * 8);
                s[ki] = __builtin_amdgcn_mfma_f32_16x16x32_bf16(qf[ks], kf, s[ki], 0, 0, 0);
            }
#pragma unroll
        for (int r = 0; r < 4; ++r) {
            float v = fmaxf(fmaxf(s[0][r], s[1][r]), fmaxf(s[2][r], s[3][r]));
#pragma unroll
            for (int off = 1; off < 16; off <<= 1) v = fmaxf(v, __shfl_xor(v, off, 16));
            const float mn = fmaxf(m_r[r], v);
            const float al = __expf(m_r[r] - mn);
            m_r[r] = mn;
            float t = __expf(s[0][r] - mn) + __expf(s[1][r] - mn)
                    + __expf(s[2][r] - mn) + __expf(s[3][r] - mn);
#pragma unroll
            for (int off = 1; off < 16; off <<= 1) t += __shfl_xor(t, off, 16);
            l_r[r] = l_r[r] * al + t;
        }
    }
    float rl[4];
#pragma unroll
    for (int r = 0; r < 4; ++r) rl[r] = 1.0f / l_r[r];

    // Pass B: recompute and write normalized probabilities (fp32)
    for (int kt = 0; kt < 32; ++kt) {
        const int kb = kt * 64;
        f32x4 s[4];
#pragma unroll
        for (int ki = 0; ki < 4; ++ki)
#pragma unroll
            for (int r = 0; r < 4; ++r) s[ki][r] = 0.0f;
#pragma unroll
        for (int ks = 0; ks < 2; ++ks)
#pragma unroll
            for (int ki = 0; ki < 4; ++ki) {
                bf16x8 kf = *(const bf16x8*)(Ku + base_b + (size_t)(kb + ki * 16 + l15) * D_MODEL + ks * 32 + quad * 8);
                s[ki] = __builtin_amdgcn_mfma_f32_16x16x32_bf16(qf[ks], kf, s[ki], 0, 0, 0);
            }
#pragma unroll
        for (int ki = 0; ki < 4; ++ki)
#pragma unroll
            for (int r = 0; r < 4; ++r) {
                const int q = qrow0 + quad * 4 + r;
                out[(size_t)(b * SEQ + q) * SEQ + kb + ki * 16 + l15] =
                    __expf(s[ki][r] - m_r[r]) * rl[r];
            }
    }
}

// ---------------------------------------------------------------------------
extern "C" void kernel_launch(void* const* d_in, const int* in_sizes, int n_in,
                              void* d_out, int out_size, void* d_ws, size_t ws_size,
                              hipStream_t stream) {
    // All inputs/outputs are FP32 (per reference). Internally bf16 MFMA.
    const float* key   = (const float*)d_in[0];
    const float* value = (const float*)d_in[1];
    const float* query = (const float*)d_in[2];
    const float* Wk = (const float*)d_in[3];
    const float* bk = (const float*)d_in[4];
    const float* Wv = (const float*)d_in[5];
    const float* bv = (const float*)d_in[6];
    const float* Wq = (const float*)d_in[7];
    const float* bq = (const float*)d_in[8];
    const float* Wo = (const float*)d_in[9];
    const float* bo = (const float*)d_in[10];

    float* out_proj = (float*)d_out;                            // 8388608 fp32 (32 MiB)
    float* out_attn = (float*)d_out + (size_t)MROWS * D_MODEL;  // 16777216 fp32 (64 MiB)

    // ws layout (40 MiB): Wt(8) | Kup(16) | Qup(16)   [all bf16]
    char* ws = (char*)d_ws;
    bf16_t* Wt  = (bf16_t*)ws;
    bf16_t* Kup = (bf16_t*)(ws + (size_t) 8 * 1024 * 1024);
    bf16_t* Qup = (bf16_t*)(ws + (size_t)24 * 1024 * 1024);
    // Vt_g (V^T per head, 16 MiB) and ctx (16 MiB) live inside the 64 MiB
    // out_attn region; both are dead before attn_h0 overwrites it at the end.
    bf16_t* Vt_g = (bf16_t*)out_attn;
    bf16_t* ctx  = Vt_g + (size_t)MROWS * D_MODEL;

    const bf16_t* Wt_k = Wt;
    const bf16_t* Wt_v = Wt + 1 * D_MODEL * D_MODEL;
    const bf16_t* Wt_q = Wt + 2 * D_MODEL * D_MODEL;
    const bf16_t* Wt_o = Wt + 3 * D_MODEL * D_MODEL;

    transpose_w<<<dim3(32, 32, 4), dim3(32, 8), 0, stream>>>(Wk, Wv, Wq, Wo, Wt);

    proj_gemm<true,  0><<<dim3(8, 64), 256, 0, stream>>>(key,   Wt_k, bk, Kup,  1.0f);
    proj_gemm<true,  2><<<dim3(8, 64), 256, 0, stream>>>(value, Wt_v, bv, Vt_g, 1.0f);   // writes V^T per head
    proj_gemm<true,  0><<<dim3(8, 64), 256, 0, stream>>>(query, Wt_q, bq, Qup,  0.125f); // 1/sqrt(64)

    flash_attn<<<dim3(32, 64), 256, 0, stream>>>(Qup, Kup, Vt_g, ctx);

    proj_gemm<false, 1><<<dim3(8, 64), 256, 0, stream>>>(ctx, Wt_o, bo, out_proj, 1.0f);

    attn_h0<<<dim3(32, 4), 256, 0, stream>>>(Qup, Kup, out_attn);
}

// Round 4
// 703.806 us; speedup vs baseline: 1.2635x; 1.2544x over previous
//
#include <hip/hip_runtime.h>
#include <stdint.h>

typedef __bf16 bf16_t;
typedef __bf16 bf16x8 __attribute__((ext_vector_type(8)));
typedef float f32x4 __attribute__((ext_vector_type(4)));

#define D_MODEL 1024
#define NH      16
#define DH      64
#define SEQ     2048
#define BATCH   4
#define MROWS   (BATCH * SEQ)   // 8192

// XOR swizzles: break the row/row+8 LDS bank aliasing (row stride 72 el = 36
// dwords == 4 mod 32). XOR on bits>=4 keeps aligned 8-el blocks contiguous,
// so all b128 accesses still work; only the base column moves.
#define VCOL(d, c) ((c) ^ ((((d) >> 3) & 3) << 4))
#define PCOL(q, c) ((c) ^ ((((q) >> 3) & 1) << 4))

// ---------------------------------------------------------------------------
// Transpose+convert 1024x1024 fp32 weights -> bf16: out[n][k] = (bf16)in[k][n]
// grid (32,32,4), block (32,8)
// ---------------------------------------------------------------------------
__global__ void transpose_w(const float* __restrict__ W0, const float* __restrict__ W1,
                            const float* __restrict__ W2, const float* __restrict__ W3,
                            bf16_t* __restrict__ out) {
    __shared__ bf16_t tile[32][33];
    const int z = blockIdx.z;
    const float* src = (z == 0) ? W0 : (z == 1) ? W1 : (z == 2) ? W2 : W3;
    bf16_t* dst = out + (size_t)z * (D_MODEL * D_MODEL);
    const int bx = blockIdx.x * 32, by = blockIdx.y * 32;
    const int tx = threadIdx.x, ty = threadIdx.y;
#pragma unroll
    for (int i = 0; i < 4; ++i)
        tile[ty + i * 8][tx] = (bf16_t)src[(size_t)(by + ty + i * 8) * D_MODEL + bx + tx];
    __syncthreads();
#pragma unroll
    for (int i = 0; i < 4; ++i)
        dst[(size_t)(bx + ty + i * 8) * D_MODEL + by + tx] = tile[tx][ty + i * 8];
}

// ---------------------------------------------------------------------------
// Projection GEMM: C[m][n] = (sum_k A[m][k]*Wt[n][k] + bias[n]) * scale
// A: (M x 1024) row-major (fp32 or bf16 per template), Wt: bf16 (= W^T)
// OUT_MODE: 0 = bf16 row-major [m][1024]
//           1 = f32  row-major [m][1024]
//           2 = bf16 per-head transposed: out[((b*16+h)*64+d)*2048 + s]
//               (m = b*2048+s, n = h*64+d)  -- feeds flash_attn's V^T operand
// grid (N/128=8, M/128), block 256 (4 waves, 2x2 of 64x64)
// ---------------------------------------------------------------------------
#define LDS_STRIDE 40
template<bool A_IS_F32, int OUT_MODE>
__global__ __launch_bounds__(256) void proj_gemm(const void* __restrict__ A_,
                                                 const bf16_t* __restrict__ Wt,
                                                 const float* __restrict__ bias,
                                                 void* __restrict__ C_,
                                                 float scale) {
    __shared__ __align__(16) bf16_t As[128 * LDS_STRIDE];
    __shared__ __align__(16) bf16_t Bs[128 * LDS_STRIDE];
    const int tid  = threadIdx.x;
    const int lane = tid & 63;
    const int w    = tid >> 6;           // wave 0..3
    const int wrow = (w >> 1) * 64;
    const int wcol = (w & 1) * 64;
    const int m0 = blockIdx.y * 128;
    const int n0 = blockIdx.x * 128;
    const int l15  = lane & 15;
    const int quad = lane >> 4;
    const int srow = tid >> 2;           // 0..63
    const int sq   = (tid & 3) * 8;      // 0,8,16,24

    f32x4 acc[4][4];
#pragma unroll
    for (int i = 0; i < 4; ++i)
#pragma unroll
        for (int j = 0; j < 4; ++j)
#pragma unroll
            for (int r = 0; r < 4; ++r) acc[i][j][r] = 0.0f;

    for (int kt = 0; kt < 32; ++kt) {
        const int k0 = kt * 32;
#pragma unroll
        for (int rd = 0; rd < 2; ++rd) {
            const int row = rd * 64 + srow;
            if (A_IS_F32) {
                const float* A = (const float*)A_;
                const float4 x = *(const float4*)(A + (size_t)(m0 + row) * D_MODEL + k0 + sq);
                const float4 y = *(const float4*)(A + (size_t)(m0 + row) * D_MODEL + k0 + sq + 4);
                bf16x8 t;
                t[0] = (bf16_t)x.x; t[1] = (bf16_t)x.y; t[2] = (bf16_t)x.z; t[3] = (bf16_t)x.w;
                t[4] = (bf16_t)y.x; t[5] = (bf16_t)y.y; t[6] = (bf16_t)y.z; t[7] = (bf16_t)y.w;
                *(bf16x8*)&As[row * LDS_STRIDE + sq] = t;
            } else {
                const bf16_t* A = (const bf16_t*)A_;
                *(bf16x8*)&As[row * LDS_STRIDE + sq] =
                    *(const bf16x8*)(A + (size_t)(m0 + row) * D_MODEL + k0 + sq);
            }
            *(bf16x8*)&Bs[row * LDS_STRIDE + sq] =
                *(const bf16x8*)(Wt + (size_t)(n0 + row) * D_MODEL + k0 + sq);
        }
        __syncthreads();
        bf16x8 af[4], bf[4];
#pragma unroll
        for (int mi = 0; mi < 4; ++mi)
            af[mi] = *(const bf16x8*)&As[(wrow + mi * 16 + l15) * LDS_STRIDE + quad * 8];
#pragma unroll
        for (int ni = 0; ni < 4; ++ni)
            bf[ni] = *(const bf16x8*)&Bs[(wcol + ni * 16 + l15) * LDS_STRIDE + quad * 8];
#pragma unroll
        for (int mi = 0; mi < 4; ++mi)
#pragma unroll
            for (int ni = 0; ni < 4; ++ni)
                acc[mi][ni] = __builtin_amdgcn_mfma_f32_16x16x32_bf16(af[mi], bf[ni], acc[mi][ni], 0, 0, 0);
        __syncthreads();
    }

#pragma unroll
    for (int ni = 0; ni < 4; ++ni) {
        const int col = n0 + wcol + ni * 16 + l15;
        const float bc = bias[col];
#pragma unroll
        for (int mi = 0; mi < 4; ++mi) {
#pragma unroll
            for (int r = 0; r < 4; ++r) {
                const int row = m0 + wrow + mi * 16 + quad * 4 + r;
                const float v = (acc[mi][ni][r] + bc) * scale;
                if (OUT_MODE == 1) {
                    ((float*)C_)[(size_t)row * D_MODEL + col] = v;
                } else if (OUT_MODE == 0) {
                    ((bf16_t*)C_)[(size_t)row * D_MODEL + col] = (bf16_t)v;
                } else {
                    // per-head transposed: [(b*16+h)*64+d][2048] <- (row=b*2048+s, col=h*64+d)
                    const int bb = row >> 11, ss = row & 2047;
                    const int hh = col >> 6,  dd = col & 63;
                    ((bf16_t*)C_)[((size_t)(bb * 16 + hh) * 64 + dd) * 2048 + ss] = (bf16_t)v;
                }
            }
        }
    }
}

// ---------------------------------------------------------------------------
// Flash attention v4 (r0 structure, conflict-free LDS):
// grid (32 q-tiles, 64 bh), block 256 (4 waves x 16 q-rows)
//   Q,K: bf16 row-major [b][seq][1024] (head offset h*64)
//   Vt_g: bf16 per-head transposed [bh][d=64][seq=2048]  (proj OUT_MODE=2)
//   ctx: bf16 row-major [b*2048+q][1024]
// vs r0: the in-kernel V transpose (16 scalar stores at ~8-way conflict =
// the 35.6M conflicts) is replaced by staging the already-transposed V^T
// from global with 2 b128 loads + 2 b128 LDS stores per thread; both LDS
// tiles are XOR-swizzled to break the d/d+8 bank aliasing.
// vs r3: V is staged ONCE per block and shared by 4 waves (r3's per-wave
// global V^T loads quadrupled L2 traffic and sat on the PV critical path).
// ---------------------------------------------------------------------------
__global__ __launch_bounds__(256) void flash_attn(const bf16_t* __restrict__ Qu,
                                                  const bf16_t* __restrict__ Ku,
                                                  const bf16_t* __restrict__ Vt_g,
                                                  bf16_t* __restrict__ ctx) {
    const int qt = blockIdx.x;           // 0..31
    const int bh = blockIdx.y;           // 0..63
    const int b = bh >> 4, h = bh & 15;
    const int tid  = threadIdx.x;
    const int lane = tid & 63;
    const int w    = tid >> 6;
    const int l15  = lane & 15;
    const int quad = lane >> 4;

    __shared__ __align__(16) bf16_t Vt[64][72];       // [d][key], swizzled cols
    __shared__ __align__(16) bf16_t Ps[4][16][72];    // [wave][q][key], swizzled cols

    const size_t base_qk = (size_t)b * SEQ * D_MODEL + (size_t)h * DH;
    const size_t base_v  = (size_t)bh * DH * SEQ;
    const int qrow0 = qt * 64 + w * 16;

    // Q fragment (A-operand): rows q on l15, feature on quad*8
    bf16x8 qf[2];
#pragma unroll
    for (int ks = 0; ks < 2; ++ks)
        qf[ks] = *(const bf16x8*)(Qu + base_qk + (size_t)(qrow0 + l15) * D_MODEL + ks * 32 + quad * 8);

    const bf16_t* kbase = Ku + base_qk + (size_t)l15 * D_MODEL + quad * 8;

    // V^T staging ids: thread covers row d = tid>>2, cols (tid&3)*16 + {0,8}
    const int vrow = tid >> 2;           // d: 0..63
    const int vc0  = (tid & 3) * 16;     // 0,16,32,48
    const bf16_t* vg = Vt_g + base_v + (size_t)vrow * SEQ;

    float m_r[4], l_r[4];
    f32x4 cacc[4];
#pragma unroll
    for (int r = 0; r < 4; ++r) { m_r[r] = -__builtin_inff(); l_r[r] = 0.0f; }
#pragma unroll
    for (int ds = 0; ds < 4; ++ds)
#pragma unroll
        for (int r = 0; r < 4; ++r) cacc[ds][r] = 0.0f;

    for (int kt = 0; kt < 32; ++kt) {
        const int kb = kt * 64;

        // ---- stage V^T tile (no transpose needed): 2 b128 global + 2 b128 LDS
        {
            bf16x8 v0 = *(const bf16x8*)(vg + kb + vc0);
            bf16x8 v1 = *(const bf16x8*)(vg + kb + vc0 + 8);
            *(bf16x8*)&Vt[vrow][VCOL(vrow, vc0)]     = v0;
            *(bf16x8*)&Vt[vrow][VCOL(vrow, vc0 + 8)] = v1;
        }

        // ---- QK^T: s[ki][r] = S[q = quad*4 + r][k = ki*16 + l15]
        f32x4 s[4];
#pragma unroll
        for (int ki = 0; ki < 4; ++ki)
#pragma unroll
            for (int r = 0; r < 4; ++r) s[ki][r] = 0.0f;
#pragma unroll
        for (int ks = 0; ks < 2; ++ks)
#pragma unroll
            for (int ki = 0; ki < 4; ++ki) {
                bf16x8 kf = *(const bf16x8*)(kbase + (size_t)(kb + ki * 16) * D_MODEL + ks * 32);
                s[ki] = __builtin_amdgcn_mfma_f32_16x16x32_bf16(qf[ks], kf, s[ki], 0, 0, 0);
            }

        // ---- online softmax per output row r (rows q = quad*4+r)
        float mn[4], al[4];
#pragma unroll
        for (int r = 0; r < 4; ++r) {
            float v = fmaxf(fmaxf(s[0][r], s[1][r]), fmaxf(s[2][r], s[3][r]));
#pragma unroll
            for (int off = 1; off < 16; off <<= 1) v = fmaxf(v, __shfl_xor(v, off, 16));
            mn[r] = fmaxf(m_r[r], v);
            al[r] = __expf(m_r[r] - mn[r]);
            m_r[r] = mn[r];
        }
        float p[4][4];
#pragma unroll
        for (int ki = 0; ki < 4; ++ki)
#pragma unroll
            for (int r = 0; r < 4; ++r) p[ki][r] = __expf(s[ki][r] - mn[r]);
#pragma unroll
        for (int r = 0; r < 4; ++r) {
            float t = p[0][r] + p[1][r] + p[2][r] + p[3][r];
#pragma unroll
            for (int off = 1; off < 16; off <<= 1) t += __shfl_xor(t, off, 16);
            l_r[r] = l_r[r] * al[r] + t;
        }
#pragma unroll
        for (int ds = 0; ds < 4; ++ds)
#pragma unroll
            for (int r = 0; r < 4; ++r) cacc[ds][r] *= al[r];

        // ---- P -> LDS (bf16), swizzled: conflict-free (4 disjoint 8-bank sets)
#pragma unroll
        for (int ki = 0; ki < 4; ++ki)
#pragma unroll
            for (int r = 0; r < 4; ++r) {
                const int q = quad * 4 + r;
                Ps[w][q][PCOL(q, ki * 16 + l15)] = (bf16_t)p[ki][r];
            }
        __syncthreads();

        // ---- PV: A = P[q=l15][k], B = V^T[d][k]
#pragma unroll
        for (int ks = 0; ks < 2; ++ks) {
            bf16x8 af = *(const bf16x8*)&Ps[w][l15][PCOL(l15, ks * 32 + quad * 8)];
#pragma unroll
            for (int ds = 0; ds < 4; ++ds) {
                const int row = ds * 16 + l15;
                bf16x8 vf = *(const bf16x8*)&Vt[row][VCOL(row, ks * 32 + quad * 8)];
                cacc[ds] = __builtin_amdgcn_mfma_f32_16x16x32_bf16(af, vf, cacc[ds], 0, 0, 0);
            }
        }
        __syncthreads();
    }

    // ---- epilogue: rows of cacc are q = quad*4 + r (same rows as m_r/l_r)
#pragma unroll
    for (int r = 0; r < 4; ++r) {
        const float rl = 1.0f / l_r[r];
        const int q = qrow0 + quad * 4 + r;
#pragma unroll
        for (int ds = 0; ds < 4; ++ds)
            ctx[(size_t)(b * SEQ + q) * D_MODEL + h * DH + ds * 16 + l15] = (bf16_t)(cacc[ds][r] * rl);
    }
}

// ---------------------------------------------------------------------------
// Head-0 attention matrix, recomputed: grid (32 q-tiles, 4 b), block 256.
// Pass A: running max/sum over keys. Pass B: write exp(s-m)/l as FP32.
// ---------------------------------------------------------------------------
__global__ __launch_bounds__(256) void attn_h0(const bf16_t* __restrict__ Qu,
                                               const bf16_t* __restrict__ Ku,
                                               float* __restrict__ out) {
    const int qt = blockIdx.x;           // 0..31
    const int b  = blockIdx.y;           // 0..3
    const int tid  = threadIdx.x;
    const int lane = tid & 63;
    const int w    = tid >> 6;
    const int l15  = lane & 15;
    const int quad = lane >> 4;

    const size_t base_b = (size_t)b * SEQ * D_MODEL;   // head 0
    const int qrow0 = qt * 64 + w * 16;

    bf16x8 qf[2];
#pragma unroll
    for (int ks = 0; ks < 2; ++ks)
        qf[ks] = *(const bf16x8*)(Qu + base_b + (size_t)(qrow0 + l15) * D_MODEL + ks * 32 + quad * 8);

    float m_r[4], l_r[4];
#pragma unroll
    for (int r = 0; r < 4; ++r) { m_r[r] = -__builtin_inff(); l_r[r] = 0.0f; }

    // Pass A: running max & sum
    for (int kt = 0; kt < 32; ++kt) {
        const int kb = kt * 64;
        f32x4 s[4];
#pragma unroll
        for (int ki = 0; ki < 4; ++ki)
#pragma unroll
            for (int r = 0; r < 4; ++r) s[ki][r] = 0.0f;
#pragma unroll
        for (int ks = 0; ks < 2; ++ks)
#pragma unroll
            for (int ki = 0; ki < 4; ++ki) {
                bf16x8 kf = *(const bf16x8*)(Ku + base_b + (size_t)(kb + ki * 16 + l15) * D_MODEL + ks * 32 + quad * 8);
                s[ki] = __builtin_amdgcn_mfma_f32_16x16x32_bf16(qf[ks], kf, s[ki], 0, 0, 0);
            }
#pragma unroll
        for (int r = 0; r < 4; ++r) {
            float v = fmaxf(fmaxf(s[0][r], s[1][r]), fmaxf(s[2][r], s[3][r]));
#pragma unroll
            for (int off = 1; off < 16; off <<= 1) v = fmaxf(v, __shfl_xor(v, off, 16));
            const float mn = fmaxf(m_r[r], v);
            const float al = __expf(m_r[r] - mn);
            m_r[r] = mn;
            float t = __expf(s[0][r] - mn) + __expf(s[1][r] - mn)
                    + __expf(s[2][r] - mn) + __expf(s[3][r] - mn);
#pragma unroll
            for (int off = 1; off < 16; off <<= 1) t += __shfl_xor(t, off, 16);
            l_r[r] = l_r[r] * al + t;
        }
    }
    float rl[4];
#pragma unroll
    for (int r = 0; r < 4; ++r) rl[r] = 1.0f / l_r[r];

    // Pass B: recompute and write normalized probabilities (fp32)
    for (int kt = 0; kt < 32; ++kt) {
        const int kb = kt * 64;
        f32x4 s[4];
#pragma unroll
        for (int ki = 0; ki < 4; ++ki)
#pragma unroll
            for (int r = 0; r < 4; ++r) s[ki][r] = 0.0f;
#pragma unroll
        for (int ks = 0; ks < 2; ++ks)
#pragma unroll
            for (int ki = 0; ki < 4; ++ki) {
                bf16x8 kf = *(const bf16x8*)(Ku + base_b + (size_t)(kb + ki * 16 + l15) * D_MODEL + ks * 32 + quad * 8);
                s[ki] = __builtin_amdgcn_mfma_f32_16x16x32_bf16(qf[ks], kf, s[ki], 0, 0, 0);
            }
#pragma unroll
        for (int ki = 0; ki < 4; ++ki)
#pragma unroll
            for (int r = 0; r < 4; ++r) {
                const int q = qrow0 + quad * 4 + r;
                out[(size_t)(b * SEQ + q) * SEQ + kb + ki * 16 + l15] =
                    __expf(s[ki][r] - m_r[r]) * rl[r];
            }
    }
}

// ---------------------------------------------------------------------------
extern "C" void kernel_launch(void* const* d_in, const int* in_sizes, int n_in,
                              void* d_out, int out_size, void* d_ws, size_t ws_size,
                              hipStream_t stream) {
    // All inputs/outputs are FP32 (per reference). Internally bf16 MFMA.
    const float* key   = (const float*)d_in[0];
    const float* value = (const float*)d_in[1];
    const float* query = (const float*)d_in[2];
    const float* Wk = (const float*)d_in[3];
    const float* bk = (const float*)d_in[4];
    const float* Wv = (const float*)d_in[5];
    const float* bv = (const float*)d_in[6];
    const float* Wq = (const float*)d_in[7];
    const float* bq = (const float*)d_in[8];
    const float* Wo = (const float*)d_in[9];
    const float* bo = (const float*)d_in[10];

    float* out_proj = (float*)d_out;                            // 8388608 fp32 (32 MiB)
    float* out_attn = (float*)d_out + (size_t)MROWS * D_MODEL;  // 16777216 fp32 (64 MiB)

    // ws layout (40 MiB): Wt(8) | Kup(16) | Qup(16)   [all bf16]
    char* ws = (char*)d_ws;
    bf16_t* Wt  = (bf16_t*)ws;
    bf16_t* Kup = (bf16_t*)(ws + (size_t) 8 * 1024 * 1024);
    bf16_t* Qup = (bf16_t*)(ws + (size_t)24 * 1024 * 1024);
    // Vt_g (V^T per head, 16 MiB) and ctx (16 MiB) live inside the 64 MiB
    // out_attn region; both are dead before attn_h0 overwrites it at the end.
    bf16_t* Vt_g = (bf16_t*)out_attn;
    bf16_t* ctx  = Vt_g + (size_t)MROWS * D_MODEL;

    const bf16_t* Wt_k = Wt;
    const bf16_t* Wt_v = Wt + 1 * D_MODEL * D_MODEL;
    const bf16_t* Wt_q = Wt + 2 * D_MODEL * D_MODEL;
    const bf16_t* Wt_o = Wt + 3 * D_MODEL * D_MODEL;

    transpose_w<<<dim3(32, 32, 4), dim3(32, 8), 0, stream>>>(Wk, Wv, Wq, Wo, Wt);

    proj_gemm<true,  0><<<dim3(8, 64), 256, 0, stream>>>(key,   Wt_k, bk, Kup,  1.0f);
    proj_gemm<true,  2><<<dim3(8, 64), 256, 0, stream>>>(value, Wt_v, bv, Vt_g, 1.0f);   // writes V^T per head
    proj_gemm<true,  0><<<dim3(8, 64), 256, 0, stream>>>(query, Wt_q, bq, Qup,  0.125f); // 1/sqrt(64)

    flash_attn<<<dim3(32, 64), 256, 0, stream>>>(Qup, Kup, Vt_g, ctx);

    proj_gemm<false, 1><<<dim3(8, 64), 256, 0, stream>>>(ctx, Wt_o, bo, out_proj, 1.0f);

    attn_h0<<<dim3(32, 4), 256, 0, stream>>>(Qup, Kup, out_attn);
}

// Round 5
// 584.339 us; speedup vs baseline: 1.5218x; 1.2044x over previous
//
#include <hip/hip_runtime.h>
#include <stdint.h>

typedef __bf16 bf16_t;
typedef __bf16 bf16x8 __attribute__((ext_vector_type(8)));
typedef float f32x4 __attribute__((ext_vector_type(4)));
typedef uint32_t u32x4 __attribute__((ext_vector_type(4)));

#define D_MODEL 1024
#define NH      16
#define DH      64
#define SEQ     2048
#define BATCH   4
#define MROWS   (BATCH * SEQ)   // 8192

// XOR swizzle for [row][72] LDS tiles (stride 72 el = 36 dw == 4 mod 32):
// XOR on bits>=4 keeps aligned 8-el chunks contiguous; rows r, r+8, r+16, r+24
// land on disjoint bank groups.
#define VCOL(d, c) ((c) ^ ((((d) >> 3) & 3) << 4))

// global_load_lds width-16 helper (dest = wave-uniform LDS base + lane*16)
__device__ __forceinline__ void gll16(const void* g, void* l) {
    __builtin_amdgcn_global_load_lds(
        (const __attribute__((address_space(1))) void*)g,
        (__attribute__((address_space(3))) void*)l, 16, 0, 0);
}

// ---------------------------------------------------------------------------
// Transpose+convert 1024x1024 fp32 weights -> bf16: out[n][k] = (bf16)in[k][n]
// grid (32,32,4), block (32,8)
// ---------------------------------------------------------------------------
__global__ void transpose_w(const float* __restrict__ W0, const float* __restrict__ W1,
                            const float* __restrict__ W2, const float* __restrict__ W3,
                            bf16_t* __restrict__ out) {
    __shared__ bf16_t tile[32][33];
    const int z = blockIdx.z;
    const float* src = (z == 0) ? W0 : (z == 1) ? W1 : (z == 2) ? W2 : W3;
    bf16_t* dst = out + (size_t)z * (D_MODEL * D_MODEL);
    const int bx = blockIdx.x * 32, by = blockIdx.y * 32;
    const int tx = threadIdx.x, ty = threadIdx.y;
#pragma unroll
    for (int i = 0; i < 4; ++i)
        tile[ty + i * 8][tx] = (bf16_t)src[(size_t)(by + ty + i * 8) * D_MODEL + bx + tx];
    __syncthreads();
#pragma unroll
    for (int i = 0; i < 4; ++i)
        dst[(size_t)(bx + ty + i * 8) * D_MODEL + by + tx] = tile[tx][ty + i * 8];
}

// ---------------------------------------------------------------------------
// fp32 -> bf16 cast (8 els/thread): enables global_load_lds in proj_gemm
// ---------------------------------------------------------------------------
__global__ __launch_bounds__(256) void cast_bf16(const float* __restrict__ in,
                                                 bf16_t* __restrict__ out, int n8) {
    const int i = blockIdx.x * 256 + threadIdx.x;
    if (i < n8) {
        const float4 x = ((const float4*)in)[i * 2];
        const float4 y = ((const float4*)in)[i * 2 + 1];
        bf16x8 t;
        t[0] = (bf16_t)x.x; t[1] = (bf16_t)x.y; t[2] = (bf16_t)x.z; t[3] = (bf16_t)x.w;
        t[4] = (bf16_t)y.x; t[5] = (bf16_t)y.y; t[6] = (bf16_t)y.z; t[7] = (bf16_t)y.w;
        ((bf16x8*)out)[i] = t;
    }
}

// ---------------------------------------------------------------------------
// Projection GEMM, m97 structure: C[m][n] = (sum_k A[m][k]*Wt[n][k] + b[n])*scale
// A: bf16 (M x 1024) row-major. Wt: bf16 (= W^T). bias fp32.
// OUT_MODE: 0 = bf16 row-major, 1 = f32 row-major,
//           2 = bf16 per-head transposed out[((b*16+h)*64+d)*2048 + s]
// grid (8, 64), block 256 (4 waves, 2x2 of 64x64), BK=32.
// Staging via global_load_lds width 16 into LINEAR [128][32] LDS (no pad;
// m97 proves the residual ds_read conflicts don't gate this structure).
// ---------------------------------------------------------------------------
template<int OUT_MODE>
__global__ __launch_bounds__(256) void proj_gemm(const bf16_t* __restrict__ A,
                                                 const bf16_t* __restrict__ Wt,
                                                 const float* __restrict__ bias,
                                                 void* __restrict__ C_,
                                                 float scale) {
    __shared__ __align__(16) bf16_t As[128 * 32];
    __shared__ __align__(16) bf16_t Bs[128 * 32];
    const int tid  = threadIdx.x;
    const int lane = tid & 63;
    const int w    = tid >> 6;           // wave 0..3
    const int wrow = (w >> 1) * 64;
    const int wcol = (w & 1) * 64;
    const int m0 = blockIdx.y * 128;
    const int n0 = blockIdx.x * 128;
    const int l15  = lane & 15;
    const int quad = lane >> 4;
    // staging: wave w covers rows [w*32, w*32+32), inst j covers 16 rows;
    // lane -> row (lane>>2), col (lane&3)*8 els. LDS dest = base + lane*16 B,
    // which equals linear [row][col] exactly (verified: (L>>2)*64+(L&3)*16 = 16L).
    const int srow = w * 32 + (lane >> 2);
    const int scol = (lane & 3) * 8;

    f32x4 acc[4][4];
#pragma unroll
    for (int i = 0; i < 4; ++i)
#pragma unroll
        for (int j = 0; j < 4; ++j)
#pragma unroll
            for (int r = 0; r < 4; ++r) acc[i][j][r] = 0.0f;

    for (int kt = 0; kt < 32; ++kt) {
        const int k0 = kt * 32;
#pragma unroll
        for (int j = 0; j < 2; ++j) {
            gll16(A  + (size_t)(m0 + srow + j * 16) * D_MODEL + k0 + scol,
                  &As[(w * 32 + j * 16) * 32]);
            gll16(Wt + (size_t)(n0 + srow + j * 16) * D_MODEL + k0 + scol,
                  &Bs[(w * 32 + j * 16) * 32]);
        }
        __syncthreads();   // drains vmcnt -> staged tile visible
        bf16x8 af[4], bf[4];
#pragma unroll
        for (int mi = 0; mi < 4; ++mi)
            af[mi] = *(const bf16x8*)&As[(wrow + mi * 16 + l15) * 32 + quad * 8];
#pragma unroll
        for (int ni = 0; ni < 4; ++ni)
            bf[ni] = *(const bf16x8*)&Bs[(wcol + ni * 16 + l15) * 32 + quad * 8];
#pragma unroll
        for (int mi = 0; mi < 4; ++mi)
#pragma unroll
            for (int ni = 0; ni < 4; ++ni)
                acc[mi][ni] = __builtin_amdgcn_mfma_f32_16x16x32_bf16(af[mi], bf[ni], acc[mi][ni], 0, 0, 0);
        __syncthreads();
    }

#pragma unroll
    for (int ni = 0; ni < 4; ++ni) {
        const int col = n0 + wcol + ni * 16 + l15;
        const float bc = bias[col];
#pragma unroll
        for (int mi = 0; mi < 4; ++mi) {
#pragma unroll
            for (int r = 0; r < 4; ++r) {
                const int row = m0 + wrow + mi * 16 + quad * 4 + r;
                const float v = (acc[mi][ni][r] + bc) * scale;
                if (OUT_MODE == 1) {
                    ((float*)C_)[(size_t)row * D_MODEL + col] = v;
                } else if (OUT_MODE == 0) {
                    ((bf16_t*)C_)[(size_t)row * D_MODEL + col] = (bf16_t)v;
                } else {
                    // per-head transposed: [(b*16+h)*64+d][2048] <- (row=b*2048+s, col=h*64+d)
                    const int bb = row >> 11, ss = row & 2047;
                    const int hh = col >> 6,  dd = col & 63;
                    ((bf16_t*)C_)[((size_t)(bb * 16 + hh) * 64 + dd) * 2048 + ss] = (bf16_t)v;
                }
            }
        }
    }
}

// ---------------------------------------------------------------------------
// pack two floats into one dword of 2 bf16 (lo = a, hi = b)
// ---------------------------------------------------------------------------
__device__ __forceinline__ uint32_t pk2(float a, float b) {
    union { bf16_t h[2]; uint32_t u; } x;
    x.h[0] = (bf16_t)a; x.h[1] = (bf16_t)b;
    return x.u;
}

// ---------------------------------------------------------------------------
// Flash attention v5: grid (32 q-tiles, 64 bh), block 256 (4 waves x 16 q-rows)
//   Q,K: bf16 row-major [b][seq][1024] (head offset h*64)
//   Vt_g: bf16 per-head transposed [bh][d=64][seq=2048]  (proj OUT_MODE=2)
//   ctx: bf16 row-major [b*2048+q][1024]
// Changes vs r4 (both from VERIFIED rounds):
//  - K staged in LDS once per block (r4 staged only V; each wave redundantly
//    re-loaded identical K fragments from global every iter = 4x VMEM traffic
//    on the QK critical path). T14 async-stage split: reg-loads for tile kt+1
//    issued right after the consuming barrier, ds_write after the end barrier,
//    so global latency hides under the whole compute phase.
//  - QK swapped orientation + lane-local softmax + in-register P exchange
//    (r2's PASSED code, verbatim) -> Ps buffer and its 16 stores deleted.
// LDS = Ks+Vs = 18432 B (same as r4). 2 barriers/iter (same as r4).
// ---------------------------------------------------------------------------
__global__ __launch_bounds__(256) void flash_attn(const bf16_t* __restrict__ Qu,
                                                  const bf16_t* __restrict__ Ku,
                                                  const bf16_t* __restrict__ Vt_g,
                                                  bf16_t* __restrict__ ctx) {
    const int qt = blockIdx.x;           // 0..31
    const int bh = blockIdx.y;           // 0..63
    const int b = bh >> 4, h = bh & 15;
    const int tid  = threadIdx.x;
    const int lane = tid & 63;
    const int w    = tid >> 6;
    const int l15  = lane & 15;
    const int quad = lane >> 4;

    __shared__ __align__(16) bf16_t Ks[64][72];   // [k][d], swizzled cols
    __shared__ __align__(16) bf16_t Vs[64][72];   // [d][k], swizzled cols

    const size_t base_qk = (size_t)b * SEQ * D_MODEL + (size_t)h * DH;
    const size_t base_v  = (size_t)bh * DH * SEQ;
    const int qrow0 = qt * 64 + w * 16;

    // Q fragment (B-operand of swapped QK): q on l15, feature on quad*8
    bf16x8 qf[2];
#pragma unroll
    for (int ks = 0; ks < 2; ++ks)
        qf[ks] = *(const bf16x8*)(Qu + base_qk + (size_t)(qrow0 + l15) * D_MODEL + ks * 32 + quad * 8);

    // staging ids: thread covers row tid>>2, 16-el col block (tid&3)*16
    const int srow = tid >> 2;           // 0..63
    const int sc0  = (tid & 3) * 16;     // 0,16,32,48
    const bf16_t* kg = Ku   + base_qk + (size_t)srow * D_MODEL + sc0;  // + kb*D_MODEL
    const bf16_t* vg = Vt_g + base_v  + (size_t)srow * SEQ + sc0;      // + kb

    bf16x8 kp0, kp1, vp0, vp1;
#define LOAD_TILE(KB)                                                    \
    do {                                                                 \
        kp0 = *(const bf16x8*)(kg + (size_t)(KB) * D_MODEL);             \
        kp1 = *(const bf16x8*)(kg + (size_t)(KB) * D_MODEL + 8);         \
        vp0 = *(const bf16x8*)(vg + (KB));                               \
        vp1 = *(const bf16x8*)(vg + (KB) + 8);                           \
    } while (0)
#define WRITE_TILE()                                                     \
    do {                                                                 \
        *(bf16x8*)&Ks[srow][VCOL(srow, sc0)]     = kp0;                  \
        *(bf16x8*)&Ks[srow][VCOL(srow, sc0 + 8)] = kp1;                  \
        *(bf16x8*)&Vs[srow][VCOL(srow, sc0)]     = vp0;                  \
        *(bf16x8*)&Vs[srow][VCOL(srow, sc0 + 8)] = vp1;                  \
    } while (0)

    float m_q = -__builtin_inff();       // running max for q = l15 (replicated over quads)
    float l_q = 0.0f;
    f32x4 cacc[4];
#pragma unroll
    for (int ds = 0; ds < 4; ++ds)
#pragma unroll
        for (int r = 0; r < 4; ++r) cacc[ds][r] = 0.0f;

    // prologue: stage tile 0
    LOAD_TILE(0);
    WRITE_TILE();

    for (int kt = 0; kt < 32; ++kt) {
        __syncthreads();                 // tile kt visible in Ks/Vs
        if (kt + 1 < 32) LOAD_TILE((kt + 1) * 64);   // latency hides under compute

        // ---- QK^T swapped: s[ki][r] = S^T[k = ki*16 + quad*4 + r][q = l15]
        f32x4 s[4];
#pragma unroll
        for (int ki = 0; ki < 4; ++ki)
#pragma unroll
            for (int r = 0; r < 4; ++r) s[ki][r] = 0.0f;
#pragma unroll
        for (int ks = 0; ks < 2; ++ks)
#pragma unroll
            for (int ki = 0; ki < 4; ++ki) {
                const int kr = ki * 16 + l15;
                bf16x8 kf = *(const bf16x8*)&Ks[kr][VCOL(kr, ks * 32 + quad * 8)];
                s[ki] = __builtin_amdgcn_mfma_f32_16x16x32_bf16(kf, qf[ks], s[ki], 0, 0, 0);
            }

        // ---- online softmax for q = l15: 16 lane-local values + 2 shfl_xor
        float v = s[0][0];
#pragma unroll
        for (int ki = 0; ki < 4; ++ki)
#pragma unroll
            for (int r = 0; r < 4; ++r) v = fmaxf(v, s[ki][r]);
        v = fmaxf(v, __shfl_xor(v, 16));
        v = fmaxf(v, __shfl_xor(v, 32));
        const float mn  = fmaxf(m_q, v);
        const float alq = __expf(m_q - mn);
        m_q = mn;

        float t = 0.0f;
        uint32_t pk_[4][2];              // pk_[ki][0]=(r0,r1) pk_[ki][1]=(r2,r3)
#pragma unroll
        for (int ki = 0; ki < 4; ++ki) {
            const float p0 = __expf(s[ki][0] - mn);
            const float p1 = __expf(s[ki][1] - mn);
            const float p2 = __expf(s[ki][2] - mn);
            const float p3 = __expf(s[ki][3] - mn);
            t += (p0 + p1) + (p2 + p3);
            pk_[ki][0] = pk2(p0, p1);
            pk_[ki][1] = pk2(p2, p3);
        }
        t += __shfl_xor(t, 16);
        t += __shfl_xor(t, 32);
        l_q = l_q * alq + t;

        // ---- rescale cacc: its rows are q = quad*4 + r -> fetch al from lane q
        float al_c[4];
#pragma unroll
        for (int r = 0; r < 4; ++r) al_c[r] = __shfl(alq, quad * 4 + r, 16);
#pragma unroll
        for (int ds = 0; ds < 4; ++ds)
#pragma unroll
            for (int r = 0; r < 4; ++r) cacc[ds][r] *= al_c[r];

        // ---- in-register P^T -> A-layout (r2 verified): af[ks][j] =
        // P[q=l15][k=ks*32+quad*8+j]; source lane l15+32*(quad&1)+16*(j>>2);
        // ki = 2*ks + (quad>>1) selected on the TARGET side after shuffling
        // both candidates (__shfl evaluates operand in the SOURCE lane).
        const int srcA = l15 + ((quad & 1) << 5);
        const bool hi  = (quad & 2) != 0;
        bf16x8 af[2];
#pragma unroll
        for (int ks = 0; ks < 2; ++ks) {
            const uint32_t a0 = pk_[2 * ks][0],     a1 = pk_[2 * ks][1];
            const uint32_t b0 = pk_[2 * ks + 1][0], b1 = pk_[2 * ks + 1][1];
            union { u32x4 d; bf16x8 v8; } cv;
            const uint32_t xa = (uint32_t)__shfl((int)a0, srcA);
            const uint32_t xb = (uint32_t)__shfl((int)b0, srcA);
            cv.d.x = hi ? xb : xa;                               // j0,j1
            const uint32_t ya = (uint32_t)__shfl((int)a1, srcA);
            const uint32_t yb = (uint32_t)__shfl((int)b1, srcA);
            cv.d.y = hi ? yb : ya;                               // j2,j3
            const uint32_t za = (uint32_t)__shfl((int)a0, srcA + 16);
            const uint32_t zb = (uint32_t)__shfl((int)b0, srcA + 16);
            cv.d.z = hi ? zb : za;                               // j4,j5
            const uint32_t wa = (uint32_t)__shfl((int)a1, srcA + 16);
            const uint32_t wb = (uint32_t)__shfl((int)b1, srcA + 16);
            cv.d.w = hi ? wb : wa;                               // j6,j7
            af[ks] = cv.v8;
        }

        // ---- PV: cacc[ds] += P[q][k] * V^T[d][k], V^T from LDS
#pragma unroll
        for (int ks = 0; ks < 2; ++ks)
#pragma unroll
            for (int ds = 0; ds < 4; ++ds) {
                const int vr = ds * 16 + l15;
                bf16x8 vf = *(const bf16x8*)&Vs[vr][VCOL(vr, ks * 32 + quad * 8)];
                cacc[ds] = __builtin_amdgcn_mfma_f32_16x16x32_bf16(af[ks], vf, cacc[ds], 0, 0, 0);
            }

        __syncthreads();                 // all waves done reading tile kt
        if (kt + 1 < 32) WRITE_TILE();   // stage tile kt+1 (vmcnt wait auto)
    }

    // ---- epilogue (r2 verified): rows of cacc are q = quad*4 + r
    float l_c[4];
#pragma unroll
    for (int r = 0; r < 4; ++r) l_c[r] = __shfl(l_q, quad * 4 + r, 16);
#pragma unroll
    for (int r = 0; r < 4; ++r) {
        const float rl = 1.0f / l_c[r];
        const int q = qrow0 + quad * 4 + r;
#pragma unroll
        for (int ds = 0; ds < 4; ++ds)
            ctx[(size_t)(b * SEQ + q) * D_MODEL + h * DH + ds * 16 + l15] = (bf16_t)(cacc[ds][r] * rl);
    }
#undef LOAD_TILE
#undef WRITE_TILE
}

// ---------------------------------------------------------------------------
// Head-0 attention matrix, recomputed: grid (32 q-tiles, 4 b), block 256.
// Pass A: running max/sum over keys. Pass B: write exp(s-m)/l as FP32.
// ---------------------------------------------------------------------------
__global__ __launch_bounds__(256) void attn_h0(const bf16_t* __restrict__ Qu,
                                               const bf16_t* __restrict__ Ku,
                                               float* __restrict__ out) {
    const int qt = blockIdx.x;           // 0..31
    const int b  = blockIdx.y;           // 0..3
    const int tid  = threadIdx.x;
    const int lane = tid & 63;
    const int w    = tid >> 6;
    const int l15  = lane & 15;
    const int quad = lane >> 4;

    const size_t base_b = (size_t)b * SEQ * D_MODEL;   // head 0
    const int qrow0 = qt * 64 + w * 16;

    bf16x8 qf[2];
#pragma unroll
    for (int ks = 0; ks < 2; ++ks)
        qf[ks] = *(const bf16x8*)(Qu + base_b + (size_t)(qrow0 + l15) * D_MODEL + ks * 32 + quad * 8);

    float m_r[4], l_r[4];
#pragma unroll
    for (int r = 0; r < 4; ++r) { m_r[r] = -__builtin_inff(); l_r[r] = 0.0f; }

    // Pass A: running max & sum
    for (int kt = 0; kt < 32; ++kt) {
        const int kb = kt * 64;
        f32x4 s[4];
#pragma unroll
        for (int ki = 0; ki < 4; ++ki)
#pragma unroll
            for (int r = 0; r < 4; ++r) s[ki][r] = 0.0f;
#pragma unroll
        for (int ks = 0; ks < 2; ++ks)
#pragma unroll
            for (int ki = 0; ki < 4; ++ki) {
                bf16x8 kf = *(const bf16x8*)(Ku + base_b + (size_t)(kb + ki * 16 + l15) * D_MODEL + ks * 32 + quad * 8);
                s[ki] = __builtin_amdgcn_mfma_f32_16x16x32_bf16(qf[ks], kf, s[ki], 0, 0, 0);
            }
#pragma unroll
        for (int r = 0; r < 4; ++r) {
            float v = fmaxf(fmaxf(s[0][r], s[1][r]), fmaxf(s[2][r], s[3][r]));
#pragma unroll
            for (int off = 1; off < 16; off <<= 1) v = fmaxf(v, __shfl_xor(v, off, 16));
            const float mn = fmaxf(m_r[r], v);
            const float al = __expf(m_r[r] - mn);
            m_r[r] = mn;
            float t = __expf(s[0][r] - mn) + __expf(s[1][r] - mn)
                    + __expf(s[2][r] - mn) + __expf(s[3][r] - mn);
#pragma unroll
            for (int off = 1; off < 16; off <<= 1) t += __shfl_xor(t, off, 16);
            l_r[r] = l_r[r] * al + t;
        }
    }
    float rl[4];
#pragma unroll
    for (int r = 0; r < 4; ++r) rl[r] = 1.0f / l_r[r];

    // Pass B: recompute and write normalized probabilities (fp32)
    for (int kt = 0; kt < 32; ++kt) {
        const int kb = kt * 64;
        f32x4 s[4];
#pragma unroll
        for (int ki = 0; ki < 4; ++ki)
#pragma unroll
            for (int r = 0; r < 4; ++r) s[ki][r] = 0.0f;
#pragma unroll
        for (int ks = 0; ks < 2; ++ks)
#pragma unroll
            for (int ki = 0; ki < 4; ++ki) {
                bf16x8 kf = *(const bf16x8*)(Ku + base_b + (size_t)(kb + ki * 16 + l15) * D_MODEL + ks * 32 + quad * 8);
                s[ki] = __builtin_amdgcn_mfma_f32_16x16x32_bf16(qf[ks], kf, s[ki], 0, 0, 0);
            }
#pragma unroll
        for (int ki = 0; ki < 4; ++ki)
#pragma unroll
            for (int r = 0; r < 4; ++r) {
                const int q = qrow0 + quad * 4 + r;
                out[(size_t)(b * SEQ + q) * SEQ + kb + ki * 16 + l15] =
                    __expf(s[ki][r] - m_r[r]) * rl[r];
            }
    }
}

// ---------------------------------------------------------------------------
extern "C" void kernel_launch(void* const* d_in, const int* in_sizes, int n_in,
                              void* d_out, int out_size, void* d_ws, size_t ws_size,
                              hipStream_t stream) {
    // All inputs/outputs are FP32 (per reference). Internally bf16 MFMA.
    const float* key   = (const float*)d_in[0];
    const float* value = (const float*)d_in[1];
    const float* query = (const float*)d_in[2];
    const float* Wk = (const float*)d_in[3];
    const float* bk = (const float*)d_in[4];
    const float* Wv = (const float*)d_in[5];
    const float* bv = (const float*)d_in[6];
    const float* Wq = (const float*)d_in[7];
    const float* bq = (const float*)d_in[8];
    const float* Wo = (const float*)d_in[9];
    const float* bo = (const float*)d_in[10];

    float* out_proj = (float*)d_out;                            // 8388608 fp32 (32 MiB)
    float* out_attn = (float*)d_out + (size_t)MROWS * D_MODEL;  // 16777216 fp32 (64 MiB)

    // ws layout (40 MiB): Wt(8) | Kup(16) | Qup(16)   [all bf16]
    char* ws = (char*)d_ws;
    bf16_t* Wt  = (bf16_t*)ws;
    bf16_t* Kup = (bf16_t*)(ws + (size_t) 8 * 1024 * 1024);
    bf16_t* Qup = (bf16_t*)(ws + (size_t)24 * 1024 * 1024);

    // out_attn region (64 MiB) scratch map -- all uses strictly serialized:
    //   R[ 0..16): Vt_g  (written by projV step 6, read by flash step 8)
    //   R[16..32): ctx   (written by flash step 8, read by projO step 9)
    //   R[32..48): C1    (key-bf16 for projK; then query-bf16 for projQ)
    //   R[48..64): C2    (value-bf16 for projV)
    // attn_h0 (step 10) overwrites the whole 64 MiB region last.
    bf16_t* Vt_g = (bf16_t*)out_attn;
    bf16_t* ctx  = Vt_g + (size_t)MROWS * D_MODEL;
    bf16_t* C1   = (bf16_t*)((char*)out_attn + ((size_t)32 << 20));
    bf16_t* C2   = (bf16_t*)((char*)out_attn + ((size_t)48 << 20));

    const bf16_t* Wt_k = Wt;
    const bf16_t* Wt_v = Wt + 1 * D_MODEL * D_MODEL;
    const bf16_t* Wt_q = Wt + 2 * D_MODEL * D_MODEL;
    const bf16_t* Wt_o = Wt + 3 * D_MODEL * D_MODEL;

    const int n8 = MROWS * D_MODEL / 8;  // 1048576 -> grid 4096

    transpose_w<<<dim3(32, 32, 4), dim3(32, 8), 0, stream>>>(Wk, Wv, Wq, Wo, Wt);

    cast_bf16<<<dim3(4096), 256, 0, stream>>>(key,   C1, n8);
    cast_bf16<<<dim3(4096), 256, 0, stream>>>(value, C2, n8);

    proj_gemm<0><<<dim3(8, 64), 256, 0, stream>>>(C1, Wt_k, bk, Kup,  1.0f);
    cast_bf16<<<dim3(4096), 256, 0, stream>>>(query, C1, n8);          // C1 (key) dead
    proj_gemm<2><<<dim3(8, 64), 256, 0, stream>>>(C2, Wt_v, bv, Vt_g, 1.0f);   // V^T per head
    proj_gemm<0><<<dim3(8, 64), 256, 0, stream>>>(C1, Wt_q, bq, Qup,  0.125f); // 1/sqrt(64)

    flash_attn<<<dim3(32, 64), 256, 0, stream>>>(Qup, Kup, Vt_g, ctx);

    proj_gemm<1><<<dim3(8, 64), 256, 0, stream>>>(ctx, Wt_o, bo, out_proj, 1.0f);

    attn_h0<<<dim3(32, 4), 256, 0, stream>>>(Qup, Kup, out_attn);
}

// Round 6
// 520.270 us; speedup vs baseline: 1.7092x; 1.1231x over previous
//
#include <hip/hip_runtime.h>
#include <stdint.h>

typedef __bf16 bf16_t;
typedef __bf16 bf16x8 __attribute__((ext_vector_type(8)));
typedef float f32x4 __attribute__((ext_vector_type(4)));
typedef uint32_t u32x4 __attribute__((ext_vector_type(4)));

#define D_MODEL 1024
#define NH      16
#define DH      64
#define SEQ     2048
#define BATCH   4
#define MROWS   (BATCH * SEQ)   // 8192

// exp2 via the native transcendental (v_exp_f32 computes 2^x).
__device__ __forceinline__ float ex2(float x) {
    float r; asm("v_exp_f32 %0, %1" : "=v"(r) : "v"(x)); return r;
}

// XOR swizzle for [row][72] LDS tiles (stride 72 el = 36 dw == 4 mod 32):
// XOR on bits>=4 keeps aligned 8-el chunks contiguous; rows r, r+8, r+16, r+24
// land on disjoint bank groups.
#define VCOL(d, c) ((c) ^ ((((d) >> 3) & 3) << 4))

// global_load_lds width-16 helper (dest = wave-uniform LDS base + lane*16)
__device__ __forceinline__ void gll16(const void* g, void* l) {
    __builtin_amdgcn_global_load_lds(
        (const __attribute__((address_space(1))) void*)g,
        (__attribute__((address_space(3))) void*)l, 16, 0, 0);
}

// ---------------------------------------------------------------------------
// Transpose+convert 1024x1024 fp32 weights -> bf16: out[n][k] = (bf16)in[k][n]
// grid (32,32,4), block (32,8)
// ---------------------------------------------------------------------------
__global__ void transpose_w(const float* __restrict__ W0, const float* __restrict__ W1,
                            const float* __restrict__ W2, const float* __restrict__ W3,
                            bf16_t* __restrict__ out) {
    __shared__ bf16_t tile[32][33];
    const int z = blockIdx.z;
    const float* src = (z == 0) ? W0 : (z == 1) ? W1 : (z == 2) ? W2 : W3;
    bf16_t* dst = out + (size_t)z * (D_MODEL * D_MODEL);
    const int bx = blockIdx.x * 32, by = blockIdx.y * 32;
    const int tx = threadIdx.x, ty = threadIdx.y;
#pragma unroll
    for (int i = 0; i < 4; ++i)
        tile[ty + i * 8][tx] = (bf16_t)src[(size_t)(by + ty + i * 8) * D_MODEL + bx + tx];
    __syncthreads();
#pragma unroll
    for (int i = 0; i < 4; ++i)
        dst[(size_t)(bx + ty + i * 8) * D_MODEL + by + tx] = tile[tx][ty + i * 8];
}

// ---------------------------------------------------------------------------
// fp32 -> bf16 cast, 3 tensors in one launch: grid (4096, 3), block 256
// ---------------------------------------------------------------------------
__global__ __launch_bounds__(256) void cast3_bf16(const float* __restrict__ i0,
                                                  const float* __restrict__ i1,
                                                  const float* __restrict__ i2,
                                                  bf16_t* __restrict__ o0,
                                                  bf16_t* __restrict__ o1,
                                                  bf16_t* __restrict__ o2, int n8) {
    const int i = blockIdx.x * 256 + threadIdx.x;
    const int z = blockIdx.y;
    const float* in  = (z == 0) ? i0 : (z == 1) ? i1 : i2;
    bf16_t*      out = (z == 0) ? o0 : (z == 1) ? o1 : o2;
    if (i < n8) {
        const float4 x = ((const float4*)in)[i * 2];
        const float4 y = ((const float4*)in)[i * 2 + 1];
        bf16x8 t;
        t[0] = (bf16_t)x.x; t[1] = (bf16_t)x.y; t[2] = (bf16_t)x.z; t[3] = (bf16_t)x.w;
        t[4] = (bf16_t)y.x; t[5] = (bf16_t)y.y; t[6] = (bf16_t)y.z; t[7] = (bf16_t)y.w;
        ((bf16x8*)out)[i] = t;
    }
}

// ---------------------------------------------------------------------------
// Projection GEMM, m97 structure: C[m][n] = (sum_k A[m][k]*Wt[n][k] + b[n])*scale
// A: bf16 (M x 1024) row-major. Wt: bf16 (= W^T). bias fp32.
// OUT_MODE: 0 = bf16 row-major, 1 = f32 row-major,
//           2 = bf16 per-head transposed out[((b*16+h)*64+d)*2048 + s]
// grid (8, 64), block 256 (4 waves, 2x2 of 64x64), BK=32.
// ---------------------------------------------------------------------------
template<int OUT_MODE>
__global__ __launch_bounds__(256) void proj_gemm(const bf16_t* __restrict__ A,
                                                 const bf16_t* __restrict__ Wt,
                                                 const float* __restrict__ bias,
                                                 void* __restrict__ C_,
                                                 float scale) {
    __shared__ __align__(16) bf16_t As[128 * 32];
    __shared__ __align__(16) bf16_t Bs[128 * 32];
    const int tid  = threadIdx.x;
    const int lane = tid & 63;
    const int w    = tid >> 6;           // wave 0..3
    const int wrow = (w >> 1) * 64;
    const int wcol = (w & 1) * 64;
    const int m0 = blockIdx.y * 128;
    const int n0 = blockIdx.x * 128;
    const int l15  = lane & 15;
    const int quad = lane >> 4;
    const int srow = w * 32 + (lane >> 2);
    const int scol = (lane & 3) * 8;

    f32x4 acc[4][4];
#pragma unroll
    for (int i = 0; i < 4; ++i)
#pragma unroll
        for (int j = 0; j < 4; ++j)
#pragma unroll
            for (int r = 0; r < 4; ++r) acc[i][j][r] = 0.0f;

    for (int kt = 0; kt < 32; ++kt) {
        const int k0 = kt * 32;
#pragma unroll
        for (int j = 0; j < 2; ++j) {
            gll16(A  + (size_t)(m0 + srow + j * 16) * D_MODEL + k0 + scol,
                  &As[(w * 32 + j * 16) * 32]);
            gll16(Wt + (size_t)(n0 + srow + j * 16) * D_MODEL + k0 + scol,
                  &Bs[(w * 32 + j * 16) * 32]);
        }
        __syncthreads();   // drains vmcnt -> staged tile visible
        bf16x8 af[4], bf[4];
#pragma unroll
        for (int mi = 0; mi < 4; ++mi)
            af[mi] = *(const bf16x8*)&As[(wrow + mi * 16 + l15) * 32 + quad * 8];
#pragma unroll
        for (int ni = 0; ni < 4; ++ni)
            bf[ni] = *(const bf16x8*)&Bs[(wcol + ni * 16 + l15) * 32 + quad * 8];
#pragma unroll
        for (int mi = 0; mi < 4; ++mi)
#pragma unroll
            for (int ni = 0; ni < 4; ++ni)
                acc[mi][ni] = __builtin_amdgcn_mfma_f32_16x16x32_bf16(af[mi], bf[ni], acc[mi][ni], 0, 0, 0);
        __syncthreads();
    }

#pragma unroll
    for (int ni = 0; ni < 4; ++ni) {
        const int col = n0 + wcol + ni * 16 + l15;
        const float bc = bias[col];
#pragma unroll
        for (int mi = 0; mi < 4; ++mi) {
#pragma unroll
            for (int r = 0; r < 4; ++r) {
                const int row = m0 + wrow + mi * 16 + quad * 4 + r;
                const float v = (acc[mi][ni][r] + bc) * scale;
                if (OUT_MODE == 1) {
                    ((float*)C_)[(size_t)row * D_MODEL + col] = v;
                } else if (OUT_MODE == 0) {
                    ((bf16_t*)C_)[(size_t)row * D_MODEL + col] = (bf16_t)v;
                } else {
                    // per-head transposed: [(b*16+h)*64+d][2048] <- (row=b*2048+s, col=h*64+d)
                    const int bb = row >> 11, ss = row & 2047;
                    const int hh = col >> 6,  dd = col & 63;
                    ((bf16_t*)C_)[((size_t)(bb * 16 + hh) * 64 + dd) * 2048 + ss] = (bf16_t)v;
                }
            }
        }
    }
}

// ---------------------------------------------------------------------------
// pack two floats into one dword of 2 bf16 (lo = a, hi = b)
// ---------------------------------------------------------------------------
__device__ __forceinline__ uint32_t pk2(float a, float b) {
    union { bf16_t h[2]; uint32_t u; } x;
    x.h[0] = (bf16_t)a; x.h[1] = (bf16_t)b;
    return x.u;
}

// ---------------------------------------------------------------------------
// Flash attention v6: grid (32 q-tiles, 64 bh), block 256 (4 waves x 16 q-rows)
//   Qu is pre-scaled by 0.125*log2(e) -> S is in log2 units; all exp -> ex2.
//   T13 defer-max (THR=8, wave-uniform): skip cacc rescale when the tile max
//   doesn't exceed the running max by >8 (P bounded by 2^8; bf16 precision is
//   scale-invariant so accuracy is unchanged).
//   For h==0, quad==0 lanes store (m, 1/l) per q-row to Mb/Lb so attn_h0
//   needs no max/sum pass.
// ---------------------------------------------------------------------------
__global__ __launch_bounds__(256) void flash_attn(const bf16_t* __restrict__ Qu,
                                                  const bf16_t* __restrict__ Ku,
                                                  const bf16_t* __restrict__ Vt_g,
                                                  bf16_t* __restrict__ ctx,
                                                  float* __restrict__ Mb,
                                                  float* __restrict__ Lb) {
    const int qt = blockIdx.x;           // 0..31
    const int bh = blockIdx.y;           // 0..63
    const int b = bh >> 4, h = bh & 15;
    const int tid  = threadIdx.x;
    const int lane = tid & 63;
    const int w    = tid >> 6;
    const int l15  = lane & 15;
    const int quad = lane >> 4;

    __shared__ __align__(16) bf16_t Ks[64][72];   // [k][d], swizzled cols
    __shared__ __align__(16) bf16_t Vs[64][72];   // [d][k], swizzled cols

    const size_t base_qk = (size_t)b * SEQ * D_MODEL + (size_t)h * DH;
    const size_t base_v  = (size_t)bh * DH * SEQ;
    const int qrow0 = qt * 64 + w * 16;

    // Q fragment (B-operand of swapped QK): q on l15, feature on quad*8
    bf16x8 qf[2];
#pragma unroll
    for (int ks = 0; ks < 2; ++ks)
        qf[ks] = *(const bf16x8*)(Qu + base_qk + (size_t)(qrow0 + l15) * D_MODEL + ks * 32 + quad * 8);

    // staging ids: thread covers row tid>>2, 16-el col block (tid&3)*16
    const int srow = tid >> 2;           // 0..63
    const int sc0  = (tid & 3) * 16;     // 0,16,32,48
    const bf16_t* kg = Ku   + base_qk + (size_t)srow * D_MODEL + sc0;  // + kb*D_MODEL
    const bf16_t* vg = Vt_g + base_v  + (size_t)srow * SEQ + sc0;      // + kb

    bf16x8 kp0, kp1, vp0, vp1;
#define LOAD_TILE(KB)                                                    \
    do {                                                                 \
        kp0 = *(const bf16x8*)(kg + (size_t)(KB) * D_MODEL);             \
        kp1 = *(const bf16x8*)(kg + (size_t)(KB) * D_MODEL + 8);         \
        vp0 = *(const bf16x8*)(vg + (KB));                               \
        vp1 = *(const bf16x8*)(vg + (KB) + 8);                           \
    } while (0)
#define WRITE_TILE()                                                     \
    do {                                                                 \
        *(bf16x8*)&Ks[srow][VCOL(srow, sc0)]     = kp0;                  \
        *(bf16x8*)&Ks[srow][VCOL(srow, sc0 + 8)] = kp1;                  \
        *(bf16x8*)&Vs[srow][VCOL(srow, sc0)]     = vp0;                  \
        *(bf16x8*)&Vs[srow][VCOL(srow, sc0 + 8)] = vp1;                  \
    } while (0)

    float m_q = -__builtin_inff();       // running max for q = l15 (replicated over quads)
    float l_q = 0.0f;
    f32x4 cacc[4];
#pragma unroll
    for (int ds = 0; ds < 4; ++ds)
#pragma unroll
        for (int r = 0; r < 4; ++r) cacc[ds][r] = 0.0f;

    // prologue: stage tile 0
    LOAD_TILE(0);
    WRITE_TILE();

    for (int kt = 0; kt < 32; ++kt) {
        __syncthreads();                 // tile kt visible in Ks/Vs
        if (kt + 1 < 32) LOAD_TILE((kt + 1) * 64);   // latency hides under compute

        // ---- QK^T swapped: s[ki][r] = S^T[k = ki*16 + quad*4 + r][q = l15]
        f32x4 s[4];
#pragma unroll
        for (int ki = 0; ki < 4; ++ki)
#pragma unroll
            for (int r = 0; r < 4; ++r) s[ki][r] = 0.0f;
#pragma unroll
        for (int ks = 0; ks < 2; ++ks)
#pragma unroll
            for (int ki = 0; ki < 4; ++ki) {
                const int kr = ki * 16 + l15;
                bf16x8 kf = *(const bf16x8*)&Ks[kr][VCOL(kr, ks * 32 + quad * 8)];
                s[ki] = __builtin_amdgcn_mfma_f32_16x16x32_bf16(kf, qf[ks], s[ki], 0, 0, 0);
            }

        // ---- online softmax for q = l15 (log2 units): 16 lane-local values
        float v = s[0][0];
#pragma unroll
        for (int ki = 0; ki < 4; ++ki)
#pragma unroll
            for (int r = 0; r < 4; ++r) v = fmaxf(v, s[ki][r]);
        v = fmaxf(v, __shfl_xor(v, 16));
        v = fmaxf(v, __shfl_xor(v, 32));

        // T13 defer-max: only rescale when the max actually grew by > 8
        if (!__all(v <= m_q + 8.0f)) {
            const float mn  = fmaxf(m_q, v);
            const float alq = ex2(m_q - mn);
            m_q = mn;
            l_q *= alq;
            float al_c[4];
#pragma unroll
            for (int r = 0; r < 4; ++r) al_c[r] = __shfl(alq, quad * 4 + r, 16);
#pragma unroll
            for (int ds = 0; ds < 4; ++ds)
#pragma unroll
                for (int r = 0; r < 4; ++r) cacc[ds][r] *= al_c[r];
        }

        float t = 0.0f;
        uint32_t pk_[4][2];              // pk_[ki][0]=(r0,r1) pk_[ki][1]=(r2,r3)
#pragma unroll
        for (int ki = 0; ki < 4; ++ki) {
            const float p0 = ex2(s[ki][0] - m_q);
            const float p1 = ex2(s[ki][1] - m_q);
            const float p2 = ex2(s[ki][2] - m_q);
            const float p3 = ex2(s[ki][3] - m_q);
            t += (p0 + p1) + (p2 + p3);
            pk_[ki][0] = pk2(p0, p1);
            pk_[ki][1] = pk2(p2, p3);
        }
        t += __shfl_xor(t, 16);
        t += __shfl_xor(t, 32);
        l_q += t;

        // ---- in-register P^T -> A-layout (r2 verified): af[ks][j] =
        // P[q=l15][k=ks*32+quad*8+j]; source lane l15+32*(quad&1)+16*(j>>2);
        // ki = 2*ks + (quad>>1) selected on the TARGET side after shuffling
        // both candidates (__shfl evaluates operand in the SOURCE lane).
        const int srcA = l15 + ((quad & 1) << 5);
        const bool hi  = (quad & 2) != 0;
        bf16x8 af[2];
#pragma unroll
        for (int ks = 0; ks < 2; ++ks) {
            const uint32_t a0 = pk_[2 * ks][0],     a1 = pk_[2 * ks][1];
            const uint32_t b0 = pk_[2 * ks + 1][0], b1 = pk_[2 * ks + 1][1];
            union { u32x4 d; bf16x8 v8; } cv;
            const uint32_t xa = (uint32_t)__shfl((int)a0, srcA);
            const uint32_t xb = (uint32_t)__shfl((int)b0, srcA);
            cv.d.x = hi ? xb : xa;                               // j0,j1
            const uint32_t ya = (uint32_t)__shfl((int)a1, srcA);
            const uint32_t yb = (uint32_t)__shfl((int)b1, srcA);
            cv.d.y = hi ? yb : ya;                               // j2,j3
            const uint32_t za = (uint32_t)__shfl((int)a0, srcA + 16);
            const uint32_t zb = (uint32_t)__shfl((int)b0, srcA + 16);
            cv.d.z = hi ? zb : za;                               // j4,j5
            const uint32_t wa = (uint32_t)__shfl((int)a1, srcA + 16);
            const uint32_t wb = (uint32_t)__shfl((int)b1, srcA + 16);
            cv.d.w = hi ? wb : wa;                               // j6,j7
            af[ks] = cv.v8;
        }

        // ---- PV: cacc[ds] += P[q][k] * V^T[d][k], V^T from LDS
#pragma unroll
        for (int ks = 0; ks < 2; ++ks)
#pragma unroll
            for (int ds = 0; ds < 4; ++ds) {
                const int vr = ds * 16 + l15;
                bf16x8 vf = *(const bf16x8*)&Vs[vr][VCOL(vr, ks * 32 + quad * 8)];
                cacc[ds] = __builtin_amdgcn_mfma_f32_16x16x32_bf16(af[ks], vf, cacc[ds], 0, 0, 0);
            }

        __syncthreads();                 // all waves done reading tile kt
        if (kt + 1 < 32) WRITE_TILE();   // stage tile kt+1 (vmcnt wait auto)
    }

    // ---- save (m, 1/l) for head 0 (attn_h0 consumes; m_q/l_q lane-local to l15)
    if (h == 0 && quad == 0) {
        const int q = b * SEQ + qrow0 + l15;
        Mb[q] = m_q;
        Lb[q] = 1.0f / l_q;
    }

    // ---- epilogue (r2 verified): rows of cacc are q = quad*4 + r
    float l_c[4];
#pragma unroll
    for (int r = 0; r < 4; ++r) l_c[r] = __shfl(l_q, quad * 4 + r, 16);
#pragma unroll
    for (int r = 0; r < 4; ++r) {
        const float rl = 1.0f / l_c[r];
        const int q = qrow0 + quad * 4 + r;
#pragma unroll
        for (int ds = 0; ds < 4; ++ds)
            ctx[(size_t)(b * SEQ + q) * D_MODEL + h * DH + ds * 16 + l15] = (bf16_t)(cacc[ds][r] * rl);
    }
#undef LOAD_TILE
#undef WRITE_TILE
}

// ---------------------------------------------------------------------------
// Head-0 attention matrix, single pass (m, 1/l precomputed by flash):
// grid (32 q-tiles, 32 k-tiles, 4 b), block 256 (4 waves x 16 q-rows).
// out[b*2048+q][k] = exp2(s - m[q]) * rl[q]   (s in log2 units, like flash)
// ---------------------------------------------------------------------------
__global__ __launch_bounds__(256) void attn_h0(const bf16_t* __restrict__ Qu,
                                               const bf16_t* __restrict__ Ku,
                                               const float* __restrict__ Mb,
                                               const float* __restrict__ Lb,
                                               float* __restrict__ out) {
    const int qt = blockIdx.x;           // 0..31
    const int ktile = blockIdx.y;        // 0..31
    const int b  = blockIdx.z;           // 0..3
    const int tid  = threadIdx.x;
    const int lane = tid & 63;
    const int w    = tid >> 6;
    const int l15  = lane & 15;
    const int quad = lane >> 4;

    const size_t base_b = (size_t)b * SEQ * D_MODEL;   // head 0
    const int qrow0 = qt * 64 + w * 16;
    const int kb = ktile * 64;

    bf16x8 qf[2];
#pragma unroll
    for (int ks = 0; ks < 2; ++ks)
        qf[ks] = *(const bf16x8*)(Qu + base_b + (size_t)(qrow0 + l15) * D_MODEL + ks * 32 + quad * 8);

    f32x4 s[4];
#pragma unroll
    for (int ki = 0; ki < 4; ++ki)
#pragma unroll
        for (int r = 0; r < 4; ++r) s[ki][r] = 0.0f;
#pragma unroll
    for (int ks = 0; ks < 2; ++ks)
#pragma unroll
        for (int ki = 0; ki < 4; ++ki) {
            bf16x8 kf = *(const bf16x8*)(Ku + base_b + (size_t)(kb + ki * 16 + l15) * D_MODEL + ks * 32 + quad * 8);
            s[ki] = __builtin_amdgcn_mfma_f32_16x16x32_bf16(qf[ks], kf, s[ki], 0, 0, 0);
        }

    float m_v[4], rl_v[4];
#pragma unroll
    for (int r = 0; r < 4; ++r) {
        const int q = b * SEQ + qrow0 + quad * 4 + r;
        m_v[r]  = Mb[q];
        rl_v[r] = Lb[q];
    }
#pragma unroll
    for (int ki = 0; ki < 4; ++ki)
#pragma unroll
        for (int r = 0; r < 4; ++r) {
            const int q = qrow0 + quad * 4 + r;
            out[(size_t)(b * SEQ + q) * SEQ + kb + ki * 16 + l15] =
                ex2(s[ki][r] - m_v[r]) * rl_v[r];
        }
}

// ---------------------------------------------------------------------------
extern "C" void kernel_launch(void* const* d_in, const int* in_sizes, int n_in,
                              void* d_out, int out_size, void* d_ws, size_t ws_size,
                              hipStream_t stream) {
    // All inputs/outputs are FP32 (per reference). Internally bf16 MFMA.
    const float* key   = (const float*)d_in[0];
    const float* value = (const float*)d_in[1];
    const float* query = (const float*)d_in[2];
    const float* Wk = (const float*)d_in[3];
    const float* bk = (const float*)d_in[4];
    const float* Wv = (const float*)d_in[5];
    const float* bv = (const float*)d_in[6];
    const float* Wq = (const float*)d_in[7];
    const float* bq = (const float*)d_in[8];
    const float* Wo = (const float*)d_in[9];
    const float* bo = (const float*)d_in[10];

    float* out_proj = (float*)d_out;                            // 8388608 fp32 (32 MiB)
    float* out_attn = (float*)d_out + (size_t)MROWS * D_MODEL;  // 16777216 fp32 (64 MiB)

    // ws layout (40 MiB): Wt(8) | Kup(16) | Qup(16)   [all bf16]
    // Mb/Lb (64 KB) overlay the START of Wt_k -- written by flash, which runs
    // AFTER projK (the only reader of Wt_k). Wt_o (offset 6 MiB) untouched.
    char* ws = (char*)d_ws;
    bf16_t* Wt  = (bf16_t*)ws;
    bf16_t* Kup = (bf16_t*)(ws + (size_t) 8 * 1024 * 1024);
    bf16_t* Qup = (bf16_t*)(ws + (size_t)24 * 1024 * 1024);
    float*  Mb  = (float*)ws;                 // 8192 fp32
    float*  Lb  = Mb + MROWS;                 // 8192 fp32 (stores 1/l)

    // out_attn region (64 MiB) scratch map -- all uses strictly serialized:
    //   R[ 0..16): Vt_g  (written by projV, read by flash)
    //   R[16..32): Cq (query-bf16, read by projQ) then ctx (flash out, projO in)
    //   R[32..48): C1 (key-bf16 for projK)
    //   R[48..64): C2 (value-bf16 for projV)
    // attn_h0 overwrites the whole 64 MiB region last.
    bf16_t* Vt_g = (bf16_t*)out_attn;
    bf16_t* Cq   = Vt_g + (size_t)MROWS * D_MODEL;
    bf16_t* ctx  = Cq;
    bf16_t* C1   = (bf16_t*)((char*)out_attn + ((size_t)32 << 20));
    bf16_t* C2   = (bf16_t*)((char*)out_attn + ((size_t)48 << 20));

    const bf16_t* Wt_k = Wt;
    const bf16_t* Wt_v = Wt + 1 * D_MODEL * D_MODEL;
    const bf16_t* Wt_q = Wt + 2 * D_MODEL * D_MODEL;
    const bf16_t* Wt_o = Wt + 3 * D_MODEL * D_MODEL;

    const int n8 = MROWS * D_MODEL / 8;  // 1048576 -> grid 4096

    transpose_w<<<dim3(32, 32, 4), dim3(32, 8), 0, stream>>>(Wk, Wv, Wq, Wo, Wt);

    cast3_bf16<<<dim3(4096, 3), 256, 0, stream>>>(key, value, query, C1, C2, Cq, n8);

    proj_gemm<0><<<dim3(8, 64), 256, 0, stream>>>(C1, Wt_k, bk, Kup,  1.0f);
    proj_gemm<2><<<dim3(8, 64), 256, 0, stream>>>(C2, Wt_v, bv, Vt_g, 1.0f);   // V^T per head
    // Q scale folds 1/sqrt(64) AND log2(e): S arrives in log2 units.
    proj_gemm<0><<<dim3(8, 64), 256, 0, stream>>>(Cq, Wt_q, bq, Qup,
                                                  0.125f * 1.4426950408889634f);

    flash_attn<<<dim3(32, 64), 256, 0, stream>>>(Qup, Kup, Vt_g, ctx, Mb, Lb);

    proj_gemm<1><<<dim3(8, 64), 256, 0, stream>>>(ctx, Wt_o, bo, out_proj, 1.0f);

    attn_h0<<<dim3(32, 32, 4), 256, 0, stream>>>(Qup, Kup, Mb, Lb, out_attn);
}